// Round 1
// baseline (1290.203 us; speedup 1.0000x reference)
//
#include <hip/hip_runtime.h>

// ---------------------------------------------------------------------------
// GATv2 x2 + MLP head, output gathered at node_idx (1000 rows).
// Pipeline: CSR build (hist/scan/scatter) -> mark needed nodes -> dense
// xl/xr GEMM -> fused per-node online-softmax aggregation (flagged only) ->
// sparse layer2 -> final MLP at selected rows.
// ---------------------------------------------------------------------------

__global__ __launch_bounds__(256)
void hist_kernel(const int* __restrict__ dst, int* __restrict__ indeg, int E)
{
    for (int e = blockIdx.x * blockDim.x + threadIdx.x; e < E;
         e += gridDim.x * blockDim.x)
        atomicAdd(&indeg[dst[e]], 1);
}

__global__ __launch_bounds__(1024)
void scan_kernel(const int* __restrict__ indeg, int* __restrict__ offs,
                 int n, int total)
{
    __shared__ int buf[1024];
    int tid = threadIdx.x;
    int chunk = (n + 1023) / 1024;
    int base = tid * chunk;
    int s = 0;
    for (int j = 0; j < chunk; ++j) {
        int idx = base + j;
        if (idx < n) s += indeg[idx];
    }
    buf[tid] = s;
    __syncthreads();
    for (int off = 1; off < 1024; off <<= 1) {
        int v = (tid >= off) ? buf[tid - off] : 0;
        __syncthreads();
        buf[tid] += v;
        __syncthreads();
    }
    int run = (tid > 0) ? buf[tid - 1] : 0;
    for (int j = 0; j < chunk; ++j) {
        int idx = base + j;
        if (idx < n) { offs[idx] = run; run += indeg[idx]; }
    }
    if (tid == 0) offs[n] = total;
}

__global__ __launch_bounds__(256)
void scatter_kernel(const int* __restrict__ src, const int* __restrict__ dst,
                    const int* __restrict__ offs, int* __restrict__ cursor,
                    int* __restrict__ eid_s, int* __restrict__ src_s, int E)
{
    for (int e = blockIdx.x * blockDim.x + threadIdx.x; e < E;
         e += gridDim.x * blockDim.x) {
        int d = dst[e];
        int pos = offs[d] + atomicAdd(&cursor[d], 1);
        eid_s[pos] = e;
        src_s[pos] = src[e];
    }
}

// mark nodes whose h1 is needed: selected nodes + srcs of their in-edges
__global__ __launch_bounds__(256)
void mark_kernel(const int* __restrict__ node_idx, const int* __restrict__ offs,
                 const int* __restrict__ src_s, int* __restrict__ flag, int n)
{
    int t = blockIdx.x * blockDim.x + threadIdx.x;
    if (t >= n) return;
    int i = node_idx[t];
    flag[i] = 1;
    int b = offs[i], e = offs[i + 1];
    for (int p = b; p < e; ++p) flag[src_s[p]] = 1;
}

// out_l = X @ Wl + bl ; out_r = X @ Wr + br   (wave per row, weights in LDS)
template <int K>
__global__ __launch_bounds__(256)
void gemm_xlr_kernel(const float* __restrict__ X,
                     const float* __restrict__ Wl, const float* __restrict__ bl,
                     const float* __restrict__ Wr, const float* __restrict__ br,
                     const int* __restrict__ flag,
                     float* __restrict__ outl, float* __restrict__ outr,
                     int rows)
{
    __shared__ float sW[2 * K * 64];
    int tid = threadIdx.x;
    for (int t = tid; t < K * 64; t += 256) {
        sW[t] = Wl[t];
        sW[K * 64 + t] = Wr[t];
    }
    __syncthreads();
    int wid = tid >> 6, lane = tid & 63;
    float bl_l = bl[lane], br_l = br[lane];
    for (int row = blockIdx.x * 4 + wid; row < rows; row += gridDim.x * 4) {
        if (flag && !flag[row]) continue;
        const float4* xrow = (const float4*)(X + (size_t)row * K);
        float accl = bl_l, accr = br_l;
#pragma unroll
        for (int q = 0; q < K / 4; ++q) {
            float4 xv = xrow[q];
            accl += xv.x * sW[(4 * q + 0) * 64 + lane]
                  + xv.y * sW[(4 * q + 1) * 64 + lane]
                  + xv.z * sW[(4 * q + 2) * 64 + lane]
                  + xv.w * sW[(4 * q + 3) * 64 + lane];
            accr += xv.x * sW[K * 64 + (4 * q + 0) * 64 + lane]
                  + xv.y * sW[K * 64 + (4 * q + 1) * 64 + lane]
                  + xv.z * sW[K * 64 + (4 * q + 2) * 64 + lane]
                  + xv.w * sW[K * 64 + (4 * q + 3) * 64 + lane];
        }
        outl[(size_t)row * 64 + lane] = accl;
        outr[(size_t)row * 64 + lane] = accr;
    }
}

// Fused GATv2 aggregation: per node (one wave), online softmax over in-edges
// + self-loop (attr = mean of incoming edge_attr, computed on the fly).
__global__ __launch_bounds__(256)
void gat_agg_kernel(const int* __restrict__ offs, const int* __restrict__ eid_s,
                    const int* __restrict__ src_s,
                    const float* __restrict__ eattr,
                    const float* __restrict__ xl, const float* __restrict__ xr,
                    const float* __restrict__ We, const float* __restrict__ att,
                    const float* __restrict__ bias,
                    const int* __restrict__ node_list,
                    const int* __restrict__ flag,
                    float* __restrict__ out, int n_items, int compact_out)
{
    int lane = threadIdx.x & 63;
    int gwid = (blockIdx.x * blockDim.x + threadIdx.x) >> 6;
    int nwaves = (gridDim.x * blockDim.x) >> 6;

    float we_c[32];  // We column for this lane's feature, register resident
#pragma unroll
    for (int k = 0; k < 32; ++k) we_c[k] = We[k * 64 + lane];
    float att_l = att[lane];
    float bias_l = bias[lane];

    for (int item = gwid; item < n_items; item += nwaves) {
        int i = node_list ? node_list[item] : item;
        if (flag && !flag[i]) continue;
        int beg = offs[i], end = offs[i + 1];
        int deg = end - beg;
        float xr_l = xr[(size_t)i * 64 + lane];

        // pass A: per-lane partial sums of incoming edge_attr (lanes mod 32)
        float lsum = 0.f;
        for (int p = beg; p < end; ++p)
            lsum += eattr[(size_t)eid_s[p] * 32 + (lane & 31)];
        float inv = 1.0f / (float)(deg > 0 ? deg : 1);

        // pass B: online softmax over in-edges + self-loop (p == end)
        float mx = -1e30f, s = 0.f, o = 0.f;
        for (int p = beg; p <= end; ++p) {
            float e = 0.f, xls;
            if (p < end) {
                const float4* a4 = (const float4*)(eattr + (size_t)eid_s[p] * 32);
#pragma unroll
                for (int q = 0; q < 8; ++q) {
                    float4 a = a4[q];
                    e += a.x * we_c[4 * q + 0] + a.y * we_c[4 * q + 1]
                       + a.z * we_c[4 * q + 2] + a.w * we_c[4 * q + 3];
                }
                int sid = src_s[p];
                xls = xl[(size_t)sid * 64 + lane];
            } else {
#pragma unroll
                for (int k = 0; k < 32; ++k) {
                    float ak = __shfl(lsum, k, 64) * inv;
                    e += ak * we_c[k];
                }
                xls = xl[(size_t)i * 64 + lane];
            }
            float mval = xls + xr_l + e;
            mval = (mval >= 0.f) ? mval : 0.2f * mval;  // leaky_relu 0.2
            float pf = mval * att_l;
#pragma unroll
            for (int d = 32; d > 0; d >>= 1) pf += __shfl_xor(pf, d, 64);
            float logit = pf;
            if (logit > mx) {
                float sc = expf(mx - logit);
                s *= sc;
                o *= sc;
                mx = logit;
            }
            float w = expf(logit - mx);
            s += w;
            o += w * xls;
        }
        float res = fmaxf(o / s + bias_l, 0.f);  // + bias, relu
        size_t orow = compact_out ? (size_t)item : (size_t)i;
        out[orow * 64 + lane] = res;
    }
}

// final MLP at selected rows: t=relu(yr@W0+b0); z=[h|t]; relu(z@W1+b1)@W2+b2
__global__ __launch_bounds__(256)
void final_kernel(const float* __restrict__ h2c, const float* __restrict__ y,
                  const float* __restrict__ W0, const float* __restrict__ b0,
                  const float* __restrict__ W1, const float* __restrict__ b1,
                  const float* __restrict__ W2, const float* __restrict__ b2,
                  const int* __restrict__ node_idx, float* __restrict__ out,
                  int n, int rf)
{
    int lane = threadIdx.x & 63;
    int r = (blockIdx.x * blockDim.x + threadIdx.x) >> 6;
    if (r >= n) return;
    int i = node_idx[r];
    int yi = i / rf;
    float y0 = y[2 * yi], y1 = y[2 * yi + 1];
    float t0 = fmaxf(y0 * W0[0] + y1 * W0[2] + b0[0], 0.f);
    float t1 = fmaxf(y0 * W0[1] + y1 * W0[3] + b0[1], 0.f);
    int j = lane & 31;
    float a = b1[j];
    const float* hrow = h2c + (size_t)r * 64;
#pragma unroll
    for (int k = 0; k < 64; ++k) a += hrow[k] * W1[k * 32 + j];
    a += t0 * W1[64 * 32 + j] + t1 * W1[65 * 32 + j];
    a = fmaxf(a, 0.f);
    float res = b2[j];
#pragma unroll
    for (int k = 0; k < 32; ++k) res += __shfl(a, k, 64) * W2[k * 32 + j];
    if (lane < 32) out[(size_t)r * 32 + j] = res;
}

extern "C" void kernel_launch(void* const* d_in, const int* in_sizes, int n_in,
                              void* d_out, int out_size, void* d_ws,
                              size_t ws_size, hipStream_t stream)
{
    const float* x     = (const float*)d_in[0];
    const float* eattr = (const float*)d_in[1];
    const float* y     = (const float*)d_in[2];
    const float* Wl1 = (const float*)d_in[3],  *bl1 = (const float*)d_in[4];
    const float* Wr1 = (const float*)d_in[5],  *br1 = (const float*)d_in[6];
    const float* We1 = (const float*)d_in[7],  *att1 = (const float*)d_in[8];
    const float* bias1 = (const float*)d_in[9];
    const float* Wl2 = (const float*)d_in[10], *bl2 = (const float*)d_in[11];
    const float* Wr2 = (const float*)d_in[12], *br2 = (const float*)d_in[13];
    const float* We2 = (const float*)d_in[14], *att2 = (const float*)d_in[15];
    const float* bias2 = (const float*)d_in[16];
    const float* W0 = (const float*)d_in[17], *b0 = (const float*)d_in[18];
    const float* W1 = (const float*)d_in[19], *b1 = (const float*)d_in[20];
    const float* W2 = (const float*)d_in[21], *b2 = (const float*)d_in[22];
    const int* eidx = (const int*)d_in[23];
    const int* nidx = (const int*)d_in[24];

    const int N = in_sizes[0] / 128;
    const int E = in_sizes[1] / 32;
    const int NSEL = in_sizes[24];
    const int NGr = in_sizes[2] / 2;
    const int rf = N / NGr;

    const int* src = eidx;
    const int* dst = eidx + E;

    // workspace layout (256B aligned)
    size_t off = 0;
    auto alloc = [&](size_t nb) {
        size_t r = off;
        off += (nb + 255) & ~(size_t)255;
        return r;
    };
    char* ws = (char*)d_ws;
    int* indeg  = (int*)(ws + alloc((size_t)N * 4));
    int* cursor = (int*)(ws + alloc((size_t)N * 4));
    int* flag   = (int*)(ws + alloc((size_t)N * 4));
    int* offs   = (int*)(ws + alloc((size_t)(N + 1) * 4));
    int* eid_s  = (int*)(ws + alloc((size_t)E * 4));
    int* src_s  = (int*)(ws + alloc((size_t)E * 4));
    float* xl  = (float*)(ws + alloc((size_t)N * 64 * 4));
    float* xr  = (float*)(ws + alloc((size_t)N * 64 * 4));
    float* h1  = (float*)(ws + alloc((size_t)N * 64 * 4));
    float* h2c = (float*)(ws + alloc((size_t)NSEL * 64 * 4));
    (void)ws_size;

    hipMemsetAsync(indeg, 0, (size_t)N * 4, stream);
    hipMemsetAsync(cursor, 0, (size_t)N * 4, stream);
    hipMemsetAsync(flag, 0, (size_t)N * 4, stream);

    // CSR by dst
    hist_kernel<<<2048, 256, 0, stream>>>(dst, indeg, E);
    scan_kernel<<<1, 1024, 0, stream>>>(indeg, offs, N, E);
    scatter_kernel<<<2048, 256, 0, stream>>>(src, dst, offs, cursor, eid_s,
                                             src_s, E);
    // nodes whose h1 we actually need
    mark_kernel<<<(NSEL + 255) / 256, 256, 0, stream>>>(nidx, offs, src_s,
                                                        flag, NSEL);
    // layer 1: dense transforms, flagged aggregation
    gemm_xlr_kernel<128><<<2048, 256, 0, stream>>>(x, Wl1, bl1, Wr1, br1,
                                                   nullptr, xl, xr, N);
    gat_agg_kernel<<<2048, 256, 0, stream>>>(offs, eid_s, src_s, eattr, xl, xr,
                                             We1, att1, bias1, nullptr, flag,
                                             h1, N, 0);
    // layer 2: flagged transforms, aggregation only at selected nodes
    gemm_xlr_kernel<64><<<2048, 256, 0, stream>>>(h1, Wl2, bl2, Wr2, br2, flag,
                                                  xl, xr, N);
    gat_agg_kernel<<<(NSEL + 3) / 4, 256, 0, stream>>>(offs, eid_s, src_s,
                                                       eattr, xl, xr, We2,
                                                       att2, bias2, nidx,
                                                       nullptr, h2c, NSEL, 1);
    // head
    final_kernel<<<(NSEL * 64 + 255) / 256, 256, 0, stream>>>(
        h2c, y, W0, b0, W1, b1, W2, b2, nidx, (float*)d_out, NSEL, rf);
}

// Round 2
// 934.880 us; speedup vs baseline: 1.3801x; 1.3801x over previous
//
#include <hip/hip_runtime.h>

// ---------------------------------------------------------------------------
// GATv2 x2 + MLP head, output at node_idx (1000 rows).
// Frontier-compact pipeline:
//   bitmaps (sel, F1=sel ∪ src-of-in-edges-of-sel) -> compact F1 CSR via
//   3 E-scans -> dense xl1 GEMM + compact xr1 GEMM -> edge-parallel logits ->
//   node-parallel online-softmax combine -> compact layer2 -> MLP head.
// ---------------------------------------------------------------------------

#define NF1CAP  24576      // cap on |F1| (expected ~15.6k)
#define SELECAP 131072     // cap on in-edges of selected (expected ~16k)

__device__ __forceinline__ int getbit(const unsigned* b, int i) {
    return (b[i >> 5] >> (i & 31)) & 1;
}

__global__ __launch_bounds__(256)
void mark_sel_kernel(const int* __restrict__ nidx, unsigned* __restrict__ selbits,
                     unsigned* __restrict__ f1bits, int n)
{
    int t = blockIdx.x * blockDim.x + threadIdx.x;
    if (t < n) {
        int i = nidx[t];
        atomicOr(&selbits[i >> 5], 1u << (i & 31));
        atomicOr(&f1bits[i >> 5], 1u << (i & 31));
    }
}

// mark srcs of edges whose dst is selected
__global__ __launch_bounds__(256)
void pass_a_kernel(const int* __restrict__ src, const int* __restrict__ dst,
                   const unsigned* __restrict__ selbits,
                   unsigned* __restrict__ f1bits, int E)
{
    for (int e = blockIdx.x * blockDim.x + threadIdx.x; e < E;
         e += gridDim.x * blockDim.x) {
        int d = dst[e];
        if (getbit(selbits, d)) {
            int s = src[e];
            atomicOr(&f1bits[s >> 5], 1u << (s & 31));
        }
    }
}

__global__ __launch_bounds__(256)
void compact_f1_kernel(const unsigned* __restrict__ f1bits, int* __restrict__ nf1,
                       int* __restrict__ f1node, int* __restrict__ slot_of, int n)
{
    int i = blockIdx.x * blockDim.x + threadIdx.x;
    if (i >= n) return;
    if (getbit(f1bits, i)) {
        int s = atomicAdd(nf1, 1);
        if (s < NF1CAP) { f1node[s] = i; slot_of[i] = s; }
        else slot_of[i] = 0;  // graceful clamp (won't trigger at this scale)
    }
}

__global__ __launch_bounds__(256)
void hist2_kernel(const int* __restrict__ dst, const unsigned* __restrict__ f1bits,
                  const int* __restrict__ slot_of, int* __restrict__ cnt, int E)
{
    for (int e = blockIdx.x * blockDim.x + threadIdx.x; e < E;
         e += gridDim.x * blockDim.x) {
        int d = dst[e];
        if (getbit(f1bits, d)) atomicAdd(&cnt[slot_of[d]], 1);
    }
}

__global__ __launch_bounds__(1024)
void scan_kernel(const int* __restrict__ cnt, const int* __restrict__ n_ptr,
                 int cap, int* __restrict__ offs, int* __restrict__ ne_out)
{
    __shared__ int buf[1024];
    int n = *n_ptr; if (n > cap) n = cap;
    int tid = threadIdx.x;
    int chunk = (n + 1023) / 1024;
    int base = tid * chunk;
    int s = 0;
    for (int j = 0; j < chunk; ++j) {
        int idx = base + j;
        if (idx < n) s += cnt[idx];
    }
    buf[tid] = s;
    __syncthreads();
    for (int off = 1; off < 1024; off <<= 1) {
        int v = (tid >= off) ? buf[tid - off] : 0;
        __syncthreads();
        buf[tid] += v;
        __syncthreads();
    }
    int run = (tid > 0) ? buf[tid - 1] : 0;
    for (int j = 0; j < chunk; ++j) {
        int idx = base + j;
        if (idx < n) { offs[idx] = run; run += cnt[idx]; }
    }
    if (tid == 1023) { offs[n] = buf[1023]; *ne_out = buf[1023]; }
}

__global__ __launch_bounds__(256)
void scatter2_kernel(const int* __restrict__ src, const int* __restrict__ dst,
                     const unsigned* __restrict__ f1bits,
                     const unsigned* __restrict__ selbits,
                     const int* __restrict__ slot_of, const int* __restrict__ aoffs,
                     int* __restrict__ cursor, int* __restrict__ aeid,
                     int* __restrict__ asrc, int* __restrict__ aslot,
                     int* __restrict__ nsel_e, int* __restrict__ selpos, int E)
{
    for (int e = blockIdx.x * blockDim.x + threadIdx.x; e < E;
         e += gridDim.x * blockDim.x) {
        int d = dst[e];
        if (!getbit(f1bits, d)) continue;
        int a = slot_of[d];
        int pos = aoffs[a] + atomicAdd(&cursor[a], 1);
        aeid[pos] = e;
        asrc[pos] = src[e];
        aslot[pos] = a;
        if (getbit(selbits, d)) {
            int q = atomicAdd(nsel_e, 1);
            if (q < SELECAP) selpos[q] = pos;
        }
    }
}

// out[rr] = X[row]@Wl + bl (and @Wr+br if TWO); row from rowlist or identity.
// 4 rows per wave to amortize LDS weight reads.
template <int K, int TWO>
__global__ __launch_bounds__(256)
void gemm_k(const float* __restrict__ X,
            const float* __restrict__ Wl, const float* __restrict__ bl,
            const float* __restrict__ Wr, const float* __restrict__ br,
            const int* __restrict__ rowlist, const int* __restrict__ cnt_ptr,
            int cnt_fixed, int cap,
            float* __restrict__ outl, float* __restrict__ outr)
{
    __shared__ float sW[(TWO + 1) * K * 64];
    int tid = threadIdx.x;
    for (int t = tid; t < K * 64; t += 256) {
        sW[t] = Wl[t];
        if (TWO) sW[K * 64 + t] = Wr[t];
    }
    __syncthreads();
    int rows = cnt_ptr ? *cnt_ptr : cnt_fixed;
    if (rows > cap) rows = cap;
    int wid = tid >> 6, lane = tid & 63;
    float blv = bl[lane];
    float brv = TWO ? br[lane] : 0.f;
    int stride = gridDim.x * 4 * 4;
    for (int base = (blockIdx.x * 4 + wid) * 4; base < rows; base += stride) {
        int nr = rows - base; if (nr > 4) nr = 4;
        const float* xp[4];
        float accl[4], accr[4];
#pragma unroll
        for (int j = 0; j < 4; ++j) {
            int rr = base + ((j < nr) ? j : 0);
            int row = rowlist ? rowlist[rr] : rr;
            xp[j] = X + (size_t)row * K;
            accl[j] = blv; accr[j] = brv;
        }
#pragma unroll 4
        for (int q = 0; q < K / 4; ++q) {
            float xc[4][4];
#pragma unroll
            for (int j = 0; j < 4; ++j) {
                float4 v = ((const float4*)xp[j])[q];
                xc[j][0] = v.x; xc[j][1] = v.y; xc[j][2] = v.z; xc[j][3] = v.w;
            }
#pragma unroll
            for (int u = 0; u < 4; ++u) {
                float wl = sW[(4 * q + u) * 64 + lane];
                float wr = TWO ? sW[K * 64 + (4 * q + u) * 64 + lane] : 0.f;
#pragma unroll
                for (int j = 0; j < 4; ++j) {
                    accl[j] += xc[j][u] * wl;
                    if (TWO) accr[j] += xc[j][u] * wr;
                }
            }
        }
        for (int j = 0; j < nr; ++j) {
            outl[(size_t)(base + j) * 64 + lane] = accl[j];
            if (TWO) outr[(size_t)(base + j) * 64 + lane] = accr[j];
        }
    }
}

// edge-parallel GATv2 logits: one wave per edge position
__global__ __launch_bounds__(256)
void logits_kernel(const int* __restrict__ cnt_ptr, int cap,
                   const int* __restrict__ pos_list,
                   const int* __restrict__ aeid, const int* __restrict__ asrc,
                   const int* __restrict__ aslot, const int* __restrict__ slot_of,
                   const float* __restrict__ eattr, const float* __restrict__ xl,
                   const float* __restrict__ xrc,
                   const float* __restrict__ We, const float* __restrict__ att,
                   float* __restrict__ alogit, int by_slot)
{
    int lane = threadIdx.x & 63;
    int gw = (blockIdx.x * blockDim.x + threadIdx.x) >> 6;
    int nw = (gridDim.x * blockDim.x) >> 6;
    float wec[32];
#pragma unroll
    for (int k = 0; k < 32; ++k) wec[k] = We[k * 64 + lane];
    float att_l = att[lane];
    int n = *cnt_ptr; if (n > cap) n = cap;
    for (int it = gw; it < n; it += nw) {
        int p = pos_list ? pos_list[it] : it;
        int e = aeid[p], s = asrc[p], a = aslot[p];
        const float4* a4 = (const float4*)(eattr + (size_t)e * 32);
        float emb = 0.f;
#pragma unroll
        for (int q = 0; q < 8; ++q) {
            float4 v = a4[q];
            emb += v.x * wec[4 * q] + v.y * wec[4 * q + 1]
                 + v.z * wec[4 * q + 2] + v.w * wec[4 * q + 3];
        }
        float xls = by_slot ? xl[(size_t)slot_of[s] * 64 + lane]
                            : xl[(size_t)s * 64 + lane];
        float m = xls + xrc[(size_t)a * 64 + lane] + emb;
        m = (m >= 0.f) ? m : 0.2f * m;
        float pf = m * att_l;
#pragma unroll
        for (int d = 32; d; d >>= 1) pf += __shfl_xor(pf, d, 64);
        if (lane == 0) alogit[p] = pf;
    }
}

// self-loop logit per node (layer1: also computes+stores mean attr)
__global__ __launch_bounds__(256)
void sloop_kernel(const int* __restrict__ cnt_ptr, int cap, int fixed_n,
                  const int* __restrict__ items, const int* __restrict__ slot_of,
                  const int* __restrict__ f1node, const int* __restrict__ aoffs,
                  const int* __restrict__ aeid, const float* __restrict__ eattr,
                  float* __restrict__ mattr, const float* __restrict__ xl,
                  const float* __restrict__ xrc, const float* __restrict__ We,
                  const float* __restrict__ att, float* __restrict__ aslogit,
                  int by_slot)
{
    int lane = threadIdx.x & 63;
    int gw = (blockIdx.x * blockDim.x + threadIdx.x) >> 6;
    int nw = (gridDim.x * blockDim.x) >> 6;
    float wec[32];
#pragma unroll
    for (int k = 0; k < 32; ++k) wec[k] = We[k * 64 + lane];
    float att_l = att[lane];
    int n;
    if (items) n = fixed_n;
    else { n = *cnt_ptr; if (n > cap) n = cap; }
    for (int it = gw; it < n; it += nw) {
        int a, i;
        float mean;
        if (!by_slot) {
            a = it; i = f1node[a];
            int beg = aoffs[a], end = aoffs[a + 1];
            float ls = 0.f;
            for (int p = beg; p < end; ++p)
                ls += eattr[(size_t)aeid[p] * 32 + (lane & 31)];
            int deg = end - beg;
            mean = ls * (1.0f / (float)(deg > 0 ? deg : 1));
            if (lane < 32) mattr[(size_t)a * 32 + lane] = mean;
        } else {
            i = items[it]; a = slot_of[i];
            mean = mattr[(size_t)a * 32 + (lane & 31)];
        }
        float emb = 0.f;
#pragma unroll
        for (int k = 0; k < 32; ++k) emb += __shfl(mean, k, 64) * wec[k];
        float xls = by_slot ? xl[(size_t)a * 64 + lane]
                            : xl[(size_t)i * 64 + lane];
        float m = xls + xrc[(size_t)a * 64 + lane] + emb;
        m = (m >= 0.f) ? m : 0.2f * m;
        float pf = m * att_l;
#pragma unroll
        for (int d = 32; d; d >>= 1) pf += __shfl_xor(pf, d, 64);
        if (lane == 0) aslogit[a] = pf;
    }
}

// node-parallel softmax + weighted aggregation
__global__ __launch_bounds__(256)
void combine_kernel(const int* __restrict__ cnt_ptr, int cap, int fixed_n,
                    const int* __restrict__ items, const int* __restrict__ slot_of,
                    const int* __restrict__ f1node, const int* __restrict__ aoffs,
                    const int* __restrict__ asrc, const float* __restrict__ alogit,
                    const float* __restrict__ aslogit, const float* __restrict__ xl,
                    const float* __restrict__ bias, float* __restrict__ out,
                    int by_slot)
{
    int lane = threadIdx.x & 63;
    int gw = (blockIdx.x * blockDim.x + threadIdx.x) >> 6;
    int nw = (gridDim.x * blockDim.x) >> 6;
    float bias_l = bias[lane];
    int n;
    if (items) n = fixed_n;
    else { n = *cnt_ptr; if (n > cap) n = cap; }
    for (int it = gw; it < n; it += nw) {
        int a, i;
        if (!by_slot) { a = it; i = f1node[a]; }
        else { i = items[it]; a = slot_of[i]; }
        int beg = aoffs[a], end = aoffs[a + 1];
        float slog = aslogit[a];
        // global max
        float mx = slog;
        for (int p = beg + lane; p < end; p += 64) mx = fmaxf(mx, alogit[p]);
#pragma unroll
        for (int d = 32; d; d >>= 1) mx = fmaxf(mx, __shfl_xor(mx, d, 64));
        // denom
        float ps = 0.f;
        for (int p = beg + lane; p < end; p += 64) ps += expf(alogit[p] - mx);
#pragma unroll
        for (int d = 32; d; d >>= 1) ps += __shfl_xor(ps, d, 64);
        float wslf = expf(slog - mx);
        float den = ps + wslf;
        // weighted sum of source transforms
        float o = wslf * (by_slot ? xl[(size_t)a * 64 + lane]
                                  : xl[(size_t)i * 64 + lane]);
        for (int p = beg; p < end; ++p) {
            float w = expf(alogit[p] - mx);
            int s = asrc[p];
            const float* row = by_slot ? xl + (size_t)slot_of[s] * 64
                                       : xl + (size_t)s * 64;
            o += w * row[lane];
        }
        out[(size_t)it * 64 + lane] = fmaxf(o / den + bias_l, 0.f);
    }
}

__global__ __launch_bounds__(256)
void final_kernel(const float* __restrict__ h2c, const float* __restrict__ y,
                  const float* __restrict__ W0, const float* __restrict__ b0,
                  const float* __restrict__ W1, const float* __restrict__ b1,
                  const float* __restrict__ W2, const float* __restrict__ b2,
                  const int* __restrict__ node_idx, float* __restrict__ out,
                  int n, int rf)
{
    int lane = threadIdx.x & 63;
    int r = (blockIdx.x * blockDim.x + threadIdx.x) >> 6;
    if (r >= n) return;
    int i = node_idx[r];
    int yi = i / rf;
    float y0 = y[2 * yi], y1 = y[2 * yi + 1];
    float t0 = fmaxf(y0 * W0[0] + y1 * W0[2] + b0[0], 0.f);
    float t1 = fmaxf(y0 * W0[1] + y1 * W0[3] + b0[1], 0.f);
    int j = lane & 31;
    float a = b1[j];
    const float* hrow = h2c + (size_t)r * 64;
#pragma unroll
    for (int k = 0; k < 64; ++k) a += hrow[k] * W1[k * 32 + j];
    a += t0 * W1[64 * 32 + j] + t1 * W1[65 * 32 + j];
    a = fmaxf(a, 0.f);
    float res = b2[j];
#pragma unroll
    for (int k = 0; k < 32; ++k) res += __shfl(a, k, 64) * W2[k * 32 + j];
    if (lane < 32) out[(size_t)r * 32 + j] = res;
}

extern "C" void kernel_launch(void* const* d_in, const int* in_sizes, int n_in,
                              void* d_out, int out_size, void* d_ws,
                              size_t ws_size, hipStream_t stream)
{
    const float* x     = (const float*)d_in[0];
    const float* eattr = (const float*)d_in[1];
    const float* y     = (const float*)d_in[2];
    const float* Wl1 = (const float*)d_in[3],  *bl1 = (const float*)d_in[4];
    const float* Wr1 = (const float*)d_in[5],  *br1 = (const float*)d_in[6];
    const float* We1 = (const float*)d_in[7],  *att1 = (const float*)d_in[8];
    const float* bias1 = (const float*)d_in[9];
    const float* Wl2 = (const float*)d_in[10], *bl2 = (const float*)d_in[11];
    const float* Wr2 = (const float*)d_in[12], *br2 = (const float*)d_in[13];
    const float* We2 = (const float*)d_in[14], *att2 = (const float*)d_in[15];
    const float* bias2 = (const float*)d_in[16];
    const float* W0 = (const float*)d_in[17], *b0 = (const float*)d_in[18];
    const float* W1 = (const float*)d_in[19], *b1 = (const float*)d_in[20];
    const float* W2 = (const float*)d_in[21], *b2 = (const float*)d_in[22];
    const int* eidx = (const int*)d_in[23];
    const int* nidx = (const int*)d_in[24];

    const int N = in_sizes[0] / 128;
    const int E = in_sizes[1] / 32;
    const int NSEL = in_sizes[24];
    const int NGr = in_sizes[2] / 2;
    const int rf = N / NGr;

    const int* src = eidx;
    const int* dst = eidx + E;

    size_t off = 0;
    auto alloc = [&](size_t nb) {
        size_t r = off;
        off += (nb + 255) & ~(size_t)255;
        return r;
    };
    char* ws = (char*)d_ws;
    const int NBW = (N + 31) / 32;  // bitmap words

    // ---- zero-init region (one memset) ----
    unsigned* selbits = (unsigned*)(ws + alloc((size_t)NBW * 4));
    unsigned* f1bits  = (unsigned*)(ws + alloc((size_t)NBW * 4));
    int* cnt    = (int*)(ws + alloc((size_t)NF1CAP * 4));
    int* cursor = (int*)(ws + alloc((size_t)NF1CAP * 4));
    int* ctrs   = (int*)(ws + alloc(256));  // [0]=nf1 [1]=ne1 [2]=nsel_e
    size_t zero_bytes = off;
    // ---- rest ----
    int* slot_of = (int*)(ws + alloc((size_t)N * 4));
    int* f1node  = (int*)(ws + alloc((size_t)NF1CAP * 4));
    int* aoffs   = (int*)(ws + alloc((size_t)(NF1CAP + 1) * 4));
    int* aeid  = (int*)(ws + alloc((size_t)E * 4));
    int* asrc  = (int*)(ws + alloc((size_t)E * 4));
    int* aslot = (int*)(ws + alloc((size_t)E * 4));
    float* alogit = (float*)(ws + alloc((size_t)E * 4));
    int* selpos   = (int*)(ws + alloc((size_t)SELECAP * 4));
    float* mattr   = (float*)(ws + alloc((size_t)NF1CAP * 32 * 4));
    float* aslogit = (float*)(ws + alloc((size_t)NF1CAP * 4));
    float* xl1  = (float*)(ws + alloc((size_t)N * 64 * 4));
    float* xr1c = (float*)(ws + alloc((size_t)NF1CAP * 64 * 4));
    float* h1c  = (float*)(ws + alloc((size_t)NF1CAP * 64 * 4));
    float* xl2c = (float*)(ws + alloc((size_t)NF1CAP * 64 * 4));
    float* xr2c = (float*)(ws + alloc((size_t)NF1CAP * 64 * 4));
    float* h2c  = (float*)(ws + alloc((size_t)NSEL * 64 * 4));
    (void)ws_size;

    int* nf1_p   = ctrs + 0;
    int* ne1_p   = ctrs + 1;
    int* nsele_p = ctrs + 2;

    hipMemsetAsync(ws, 0, zero_bytes, stream);

    // frontier + compact CSR
    mark_sel_kernel<<<(NSEL + 255) / 256, 256, 0, stream>>>(nidx, selbits,
                                                            f1bits, NSEL);
    pass_a_kernel<<<2048, 256, 0, stream>>>(src, dst, selbits, f1bits, E);
    compact_f1_kernel<<<(N + 255) / 256, 256, 0, stream>>>(f1bits, nf1_p,
                                                           f1node, slot_of, N);
    hist2_kernel<<<2048, 256, 0, stream>>>(dst, f1bits, slot_of, cnt, E);
    scan_kernel<<<1, 1024, 0, stream>>>(cnt, nf1_p, NF1CAP, aoffs, ne1_p);
    scatter2_kernel<<<2048, 256, 0, stream>>>(src, dst, f1bits, selbits,
                                              slot_of, aoffs, cursor, aeid,
                                              asrc, aslot, nsele_p, selpos, E);
    // layer-1 transforms
    gemm_k<128, 0><<<2048, 256, 0, stream>>>(x, Wl1, bl1, nullptr, nullptr,
                                             nullptr, nullptr, N, N, xl1,
                                             nullptr);
    gemm_k<128, 0><<<1024, 256, 0, stream>>>(x, Wr1, br1, nullptr, nullptr,
                                             f1node, nf1_p, 0, NF1CAP, xr1c,
                                             nullptr);
    // layer-1 attention + aggregation
    logits_kernel<<<4096, 256, 0, stream>>>(ne1_p, E, nullptr, aeid, asrc,
                                            aslot, slot_of, eattr, xl1, xr1c,
                                            We1, att1, alogit, 0);
    sloop_kernel<<<1024, 256, 0, stream>>>(nf1_p, NF1CAP, 0, nullptr, slot_of,
                                           f1node, aoffs, aeid, eattr, mattr,
                                           xl1, xr1c, We1, att1, aslogit, 0);
    combine_kernel<<<1024, 256, 0, stream>>>(nf1_p, NF1CAP, 0, nullptr,
                                             slot_of, f1node, aoffs, asrc,
                                             alogit, aslogit, xl1, bias1, h1c,
                                             0);
    // layer-2 transforms (compact over F1)
    gemm_k<64, 1><<<1024, 256, 0, stream>>>(h1c, Wl2, bl2, Wr2, br2, nullptr,
                                            nf1_p, 0, NF1CAP, xl2c, xr2c);
    // layer-2 attention + aggregation at selected nodes
    logits_kernel<<<256, 256, 0, stream>>>(nsele_p, SELECAP, selpos, aeid,
                                           asrc, aslot, slot_of, eattr, xl2c,
                                           xr2c, We2, att2, alogit, 1);
    sloop_kernel<<<(NSEL + 3) / 4, 256, 0, stream>>>(nullptr, 0, NSEL, nidx,
                                                     slot_of, f1node, aoffs,
                                                     aeid, eattr, mattr, xl2c,
                                                     xr2c, We2, att2, aslogit,
                                                     1);
    combine_kernel<<<(NSEL + 3) / 4, 256, 0, stream>>>(nullptr, 0, NSEL, nidx,
                                                       slot_of, f1node, aoffs,
                                                       asrc, alogit, aslogit,
                                                       xl2c, bias2, h2c, 1);
    // head
    final_kernel<<<(NSEL * 64 + 255) / 256, 256, 0, stream>>>(
        h2c, y, W0, b0, W1, b1, W2, b2, nidx, (float*)d_out, NSEL, rf);
}

// Round 4
// 814.273 us; speedup vs baseline: 1.5845x; 1.1481x over previous
//
#include <hip/hip_runtime.h>

// ---------------------------------------------------------------------------
// GATv2 x2 + MLP head, output at node_idx (1000 rows).
// Frontier-compact pipeline, packed-record CSR:
//   mark sel/F1 bitmaps (+full indeg) -> compact F1 -> scan -> scatter of
//   packed u64 {eid|src|slot} -> fused dense-xl1/compact-xr1 GEMM ->
//   edge-parallel logits -> merged self-loop+combine (layer1) -> compact
//   layer2 GEMM -> per-sel-node sub-wave logits -> merged tail (self-loop +
//   combine + MLP head).
// ---------------------------------------------------------------------------

#define NF1CAP 24576   // cap on |F1| (expected ~15.6k)

__device__ __forceinline__ int getbit(const unsigned* b, int i) {
    return (b[i >> 5] >> (i & 31)) & 1;
}

__global__ __launch_bounds__(256)
void mark_sel_kernel(const int* __restrict__ nidx, unsigned* __restrict__ selbits,
                     unsigned* __restrict__ f1bits, int n)
{
    int t = blockIdx.x * blockDim.x + threadIdx.x;
    if (t < n) {
        int i = nidx[t];
        atomicOr(&selbits[i >> 5], 1u << (i & 31));
        atomicOr(&f1bits[i >> 5], 1u << (i & 31));
    }
}

// full in-degree histogram + mark srcs of edges whose dst is selected
__global__ __launch_bounds__(256)
void pass_a_kernel(const int* __restrict__ src, const int* __restrict__ dst,
                   const unsigned* __restrict__ selbits,
                   unsigned* __restrict__ f1bits, int* __restrict__ indeg, int E)
{
    for (int e = blockIdx.x * blockDim.x + threadIdx.x; e < E;
         e += gridDim.x * blockDim.x) {
        int d = dst[e];
        atomicAdd(&indeg[d], 1);
        if (getbit(selbits, d)) {
            int s = src[e];
            atomicOr(&f1bits[s >> 5], 1u << (s & 31));
        }
    }
}

__global__ __launch_bounds__(256)
void compact_f1_kernel(const unsigned* __restrict__ f1bits, int* __restrict__ nf1,
                       int* __restrict__ f1node, int* __restrict__ slot_of, int n)
{
    int i = blockIdx.x * blockDim.x + threadIdx.x;
    if (i >= n) return;
    if (getbit(f1bits, i)) {
        int s = atomicAdd(nf1, 1);   // compiler wave-coalesces count-atomics
        if (s < NF1CAP) { f1node[s] = i; slot_of[i] = s; }
        else slot_of[i] = 0;
    }
}

__global__ __launch_bounds__(1024)
void scan_kernel(const int* __restrict__ indeg, const int* __restrict__ f1node,
                 const int* __restrict__ n_ptr, int cap,
                 int* __restrict__ offs, int* __restrict__ ne_out)
{
    __shared__ int buf[1024];
    int n = *n_ptr; if (n > cap) n = cap;
    int tid = threadIdx.x;
    int chunk = (n + 1023) / 1024;
    int base = tid * chunk;
    int s = 0;
    for (int j = 0; j < chunk; ++j) {
        int idx = base + j;
        if (idx < n) s += indeg[f1node[idx]];
    }
    buf[tid] = s;
    __syncthreads();
    for (int off = 1; off < 1024; off <<= 1) {
        int v = (tid >= off) ? buf[tid - off] : 0;
        __syncthreads();
        buf[tid] += v;
        __syncthreads();
    }
    int run = (tid > 0) ? buf[tid - 1] : 0;
    for (int j = 0; j < chunk; ++j) {
        int idx = base + j;
        if (idx < n) { offs[idx] = run; run += indeg[f1node[idx]]; }
    }
    if (tid == 1023) { offs[n] = buf[1023]; *ne_out = buf[1023]; }
}

// packed record: eid[0:21) | src[21:38) | slot[38:53)
__global__ __launch_bounds__(256)
void scatter_kernel(const int* __restrict__ src, const int* __restrict__ dst,
                    const unsigned* __restrict__ f1bits,
                    const int* __restrict__ slot_of, const int* __restrict__ aoffs,
                    int* __restrict__ cursor,
                    unsigned long long* __restrict__ apack, int E)
{
    for (int e = blockIdx.x * blockDim.x + threadIdx.x; e < E;
         e += gridDim.x * blockDim.x) {
        int d = dst[e];
        if (!getbit(f1bits, d)) continue;
        int a = slot_of[d];
        int pos = aoffs[a] + atomicAdd(&cursor[a], 1);
        apack[pos] = (unsigned long long)(unsigned)e
                   | ((unsigned long long)(unsigned)src[e] << 21)
                   | ((unsigned long long)(unsigned)a << 38);
    }
}

// fused: blocks [0,gb_dense) -> outl[row] = X[row]@Wl+bl for all ndense rows;
//        blocks [gb_dense,..) -> outr[slot] = X[f1node[slot]]@Wr+br.
template <int K>
__global__ __launch_bounds__(256)
void gemm_fused_kernel(const float* __restrict__ X,
                       const float* __restrict__ Wl, const float* __restrict__ bl,
                       const float* __restrict__ Wr, const float* __restrict__ br,
                       const int* __restrict__ f1node, const int* __restrict__ nf1_p,
                       int ndense, int gb_dense,
                       float* __restrict__ outl, float* __restrict__ outr)
{
    __shared__ float sW[K * 64];
    int dense = (int)blockIdx.x < gb_dense;
    const float* W = dense ? Wl : Wr;
    int tid = threadIdx.x;
    for (int t = tid; t < K * 64; t += 256) sW[t] = W[t];
    __syncthreads();
    int rows, bid, nb;
    const int* rowlist;
    const float* bias;
    float* out;
    if (dense) {
        rows = ndense; bid = blockIdx.x; nb = gb_dense;
        rowlist = nullptr; bias = bl; out = outl;
    } else {
        rows = *nf1_p; if (rows > NF1CAP) rows = NF1CAP;
        bid = blockIdx.x - gb_dense; nb = gridDim.x - gb_dense;
        rowlist = f1node; bias = br; out = outr;
    }
    int wid = tid >> 6, lane = tid & 63;
    float bv = bias[lane];
    int stride = nb * 16;
    for (int base = (bid * 4 + wid) * 4; base < rows; base += stride) {
        int nr = rows - base; if (nr > 4) nr = 4;
        const float* xp[4];
        float acc[4];
#pragma unroll
        for (int j = 0; j < 4; ++j) {
            int rr = base + ((j < nr) ? j : 0);
            int row = rowlist ? rowlist[rr] : rr;
            xp[j] = X + (size_t)row * K;
            acc[j] = bv;
        }
#pragma unroll 4
        for (int q = 0; q < K / 4; ++q) {
            float xc[4][4];
#pragma unroll
            for (int j = 0; j < 4; ++j) {
                float4 v = ((const float4*)xp[j])[q];
                xc[j][0] = v.x; xc[j][1] = v.y; xc[j][2] = v.z; xc[j][3] = v.w;
            }
#pragma unroll
            for (int u = 0; u < 4; ++u) {
                float w = sW[(4 * q + u) * 64 + lane];
#pragma unroll
                for (int j = 0; j < 4; ++j) acc[j] += xc[j][u] * w;
            }
        }
        for (int j = 0; j < nr; ++j)
            out[(size_t)(base + j) * 64 + lane] = acc[j];
    }
}

// compact layer-2 transform: both xl2c and xr2c over nf1 rows of h1c (K=64)
__global__ __launch_bounds__(256)
void gemm2_kernel(const float* __restrict__ X,
                  const float* __restrict__ Wl, const float* __restrict__ bl,
                  const float* __restrict__ Wr, const float* __restrict__ br,
                  const int* __restrict__ nf1_p,
                  float* __restrict__ outl, float* __restrict__ outr)
{
    __shared__ float sW[2 * 64 * 64];
    int tid = threadIdx.x;
    for (int t = tid; t < 64 * 64; t += 256) {
        sW[t] = Wl[t];
        sW[64 * 64 + t] = Wr[t];
    }
    __syncthreads();
    int rows = *nf1_p; if (rows > NF1CAP) rows = NF1CAP;
    int wid = tid >> 6, lane = tid & 63;
    float blv = bl[lane], brv = br[lane];
    int stride = gridDim.x * 16;
    for (int base = (blockIdx.x * 4 + wid) * 4; base < rows; base += stride) {
        int nr = rows - base; if (nr > 4) nr = 4;
        const float* xp[4];
        float accl[4], accr[4];
#pragma unroll
        for (int j = 0; j < 4; ++j) {
            int rr = base + ((j < nr) ? j : 0);
            xp[j] = X + (size_t)rr * 64;
            accl[j] = blv; accr[j] = brv;
        }
#pragma unroll 4
        for (int q = 0; q < 16; ++q) {
            float xc[4][4];
#pragma unroll
            for (int j = 0; j < 4; ++j) {
                float4 v = ((const float4*)xp[j])[q];
                xc[j][0] = v.x; xc[j][1] = v.y; xc[j][2] = v.z; xc[j][3] = v.w;
            }
#pragma unroll
            for (int u = 0; u < 4; ++u) {
                float wl = sW[(4 * q + u) * 64 + lane];
                float wr = sW[64 * 64 + (4 * q + u) * 64 + lane];
#pragma unroll
                for (int j = 0; j < 4; ++j) {
                    accl[j] += xc[j][u] * wl;
                    accr[j] += xc[j][u] * wr;
                }
            }
        }
        for (int j = 0; j < nr; ++j) {
            outl[(size_t)(base + j) * 64 + lane] = accl[j];
            outr[(size_t)(base + j) * 64 + lane] = accr[j];
        }
    }
}

// edge-parallel layer-1 logits: one wave per CSR position
__global__ __launch_bounds__(256)
void logits1_kernel(const int* __restrict__ ne_ptr,
                    const unsigned long long* __restrict__ apack,
                    const float* __restrict__ eattr, const float* __restrict__ xl,
                    const float* __restrict__ xrc, const float* __restrict__ We,
                    const float* __restrict__ att, float* __restrict__ alogit)
{
    int lane = threadIdx.x & 63;
    int gw = (blockIdx.x * blockDim.x + threadIdx.x) >> 6;
    int nw = (gridDim.x * blockDim.x) >> 6;
    float wec[32];
#pragma unroll
    for (int k = 0; k < 32; ++k) wec[k] = We[k * 64 + lane];
    float att_l = att[lane];
    int n = *ne_ptr;
    for (int p = gw; p < n; p += nw) {
        unsigned long long rec = apack[p];
        int e = (int)(rec & 0x1FFFFF);
        int s = (int)((rec >> 21) & 0x1FFFF);
        int a = (int)((rec >> 38) & 0x7FFF);
        const float4* a4 = (const float4*)(eattr + (size_t)e * 32);
        float emb = 0.f;
#pragma unroll
        for (int q = 0; q < 8; ++q) {
            float4 v = a4[q];
            emb += v.x * wec[4 * q] + v.y * wec[4 * q + 1]
                 + v.z * wec[4 * q + 2] + v.w * wec[4 * q + 3];
        }
        float m = xl[(size_t)s * 64 + lane] + xrc[(size_t)a * 64 + lane] + emb;
        m = (m >= 0.f) ? m : 0.2f * m;
        float pf = m * att_l;
#pragma unroll
        for (int d = 32; d; d >>= 1) pf += __shfl_xor(pf, d, 64);
        if (lane == 0) alogit[p] = pf;
    }
}

// layer-2 logits: 16 sub-waves per selected node over its CSR range
__global__ __launch_bounds__(256)
void logits2_kernel(const int* __restrict__ nidx, const int* __restrict__ slot_of,
                    const int* __restrict__ aoffs,
                    const unsigned long long* __restrict__ apack,
                    const float* __restrict__ eattr, const float* __restrict__ xl2c,
                    const float* __restrict__ xr2c, const float* __restrict__ We,
                    const float* __restrict__ att, float* __restrict__ alogit,
                    int nsel)
{
    int lane = threadIdx.x & 63;
    int w = (blockIdx.x * blockDim.x + threadIdx.x) >> 6;
    int item = w >> 4, sub = w & 15;
    if (item >= nsel) return;
    float wec[32];
#pragma unroll
    for (int k = 0; k < 32; ++k) wec[k] = We[k * 64 + lane];
    float att_l = att[lane];
    int i = nidx[item];
    int a = slot_of[i];
    int beg = aoffs[a], end = aoffs[a + 1];
    float xr_l = xr2c[(size_t)a * 64 + lane];
    for (int p = beg + sub; p < end; p += 16) {
        unsigned long long rec = apack[p];
        int e = (int)(rec & 0x1FFFFF);
        int s = (int)((rec >> 21) & 0x1FFFF);
        const float4* a4 = (const float4*)(eattr + (size_t)e * 32);
        float emb = 0.f;
#pragma unroll
        for (int q = 0; q < 8; ++q) {
            float4 v = a4[q];
            emb += v.x * wec[4 * q] + v.y * wec[4 * q + 1]
                 + v.z * wec[4 * q + 2] + v.w * wec[4 * q + 3];
        }
        float m = xl2c[(size_t)slot_of[s] * 64 + lane] + xr_l + emb;
        m = (m >= 0.f) ? m : 0.2f * m;
        float pf = m * att_l;
#pragma unroll
        for (int d = 32; d; d >>= 1) pf += __shfl_xor(pf, d, 64);
        if (lane == 0) alogit[p] = pf;
    }
}

// layer-1 merged: mean-attr + self-logit + softmax combine -> h1c, mattr
__global__ __launch_bounds__(256)
void sc1_kernel(const int* __restrict__ nf1_p, const int* __restrict__ f1node,
                const int* __restrict__ aoffs,
                const unsigned long long* __restrict__ apack,
                const float* __restrict__ eattr, float* __restrict__ mattr,
                const float* __restrict__ xl1, const float* __restrict__ xr1c,
                const float* __restrict__ We, const float* __restrict__ att,
                const float* __restrict__ alogit, const float* __restrict__ bias,
                float* __restrict__ h1c)
{
    int lane = threadIdx.x & 63, l32 = lane & 31, half = lane >> 5;
    int gw = (blockIdx.x * blockDim.x + threadIdx.x) >> 6;
    int nw = (gridDim.x * blockDim.x) >> 6;
    float wec[32];
#pragma unroll
    for (int k = 0; k < 32; ++k) wec[k] = We[k * 64 + lane];
    float att_l = att[lane];
    float bias_l = bias[lane];
    int n = *nf1_p; if (n > NF1CAP) n = NF1CAP;
    for (int a = gw; a < n; a += nw) {
        int i = f1node[a];
        int beg = aoffs[a], end = aoffs[a + 1], deg = end - beg;
        // mean incoming edge_attr (two edges per iteration)
        float ls = 0.f;
        for (int p = beg + half; p < end; p += 2) {
            int e = (int)(apack[p] & 0x1FFFFF);
            ls += eattr[(size_t)e * 32 + l32];
        }
        ls += __shfl_xor(ls, 32, 64);
        float mean = ls * (1.0f / (float)(deg > 0 ? deg : 1));
        if (lane < 32) mattr[(size_t)a * 32 + lane] = mean;
        // self-loop logit
        float emb = 0.f;
#pragma unroll
        for (int k = 0; k < 32; ++k) emb += __shfl(mean, k, 64) * wec[k];
        float xls = xl1[(size_t)i * 64 + lane];
        float m = xls + xr1c[(size_t)a * 64 + lane] + emb;
        m = (m >= 0.f) ? m : 0.2f * m;
        float pf = m * att_l;
#pragma unroll
        for (int d = 32; d; d >>= 1) pf += __shfl_xor(pf, d, 64);
        float slog = pf;
        // softmax over in-edges + self
        float mx = slog;
        for (int p = beg + lane; p < end; p += 64) mx = fmaxf(mx, alogit[p]);
#pragma unroll
        for (int d = 32; d; d >>= 1) mx = fmaxf(mx, __shfl_xor(mx, d, 64));
        float ps = 0.f;
        for (int p = beg + lane; p < end; p += 64) ps += __expf(alogit[p] - mx);
#pragma unroll
        for (int d = 32; d; d >>= 1) ps += __shfl_xor(ps, d, 64);
        float wself = __expf(slog - mx);
        float den = ps + wself;
        float o = wself * xls;
        for (int p = beg; p < end; ++p) {
            float wgt = __expf(alogit[p] - mx);
            int s = (int)((apack[p] >> 21) & 0x1FFFF);
            o += wgt * xl1[(size_t)s * 64 + lane];
        }
        h1c[(size_t)a * 64 + lane] = fmaxf(o / den + bias_l, 0.f);
    }
}

// layer-2 merged tail per selected row: self-logit + combine + MLP head
__global__ __launch_bounds__(256)
void tail2_kernel(const int* __restrict__ nidx, const int* __restrict__ slot_of,
                  const int* __restrict__ aoffs,
                  const unsigned long long* __restrict__ apack,
                  const float* __restrict__ mattr, const float* __restrict__ xl2c,
                  const float* __restrict__ xr2c, const float* __restrict__ We,
                  const float* __restrict__ att, const float* __restrict__ alogit,
                  const float* __restrict__ bias, const float* __restrict__ y,
                  const float* __restrict__ W0, const float* __restrict__ b0,
                  const float* __restrict__ W1, const float* __restrict__ b1,
                  const float* __restrict__ W2, const float* __restrict__ b2,
                  float* __restrict__ out, int nsel, int rf)
{
    int lane = threadIdx.x & 63;
    int r = (blockIdx.x * blockDim.x + threadIdx.x) >> 6;
    if (r >= nsel) return;
    float wec[32];
#pragma unroll
    for (int k = 0; k < 32; ++k) wec[k] = We[k * 64 + lane];
    float att_l = att[lane];
    float bias_l = bias[lane];
    int i = nidx[r];
    int a = slot_of[i];
    int beg = aoffs[a], end = aoffs[a + 1];
    float mean = mattr[(size_t)a * 32 + (lane & 31)];
    float emb = 0.f;
#pragma unroll
    for (int k = 0; k < 32; ++k) emb += __shfl(mean, k, 64) * wec[k];
    float xls = xl2c[(size_t)a * 64 + lane];
    float m = xls + xr2c[(size_t)a * 64 + lane] + emb;
    m = (m >= 0.f) ? m : 0.2f * m;
    float pf = m * att_l;
#pragma unroll
    for (int d = 32; d; d >>= 1) pf += __shfl_xor(pf, d, 64);
    float slog = pf;
    float mx = slog;
    for (int p = beg + lane; p < end; p += 64) mx = fmaxf(mx, alogit[p]);
#pragma unroll
    for (int d = 32; d; d >>= 1) mx = fmaxf(mx, __shfl_xor(mx, d, 64));
    float ps = 0.f;
    for (int p = beg + lane; p < end; p += 64) ps += __expf(alogit[p] - mx);
#pragma unroll
    for (int d = 32; d; d >>= 1) ps += __shfl_xor(ps, d, 64);
    float wself = __expf(slog - mx);
    float den = ps + wself;
    float o = wself * xls;
    for (int p = beg; p < end; ++p) {
        float wgt = __expf(alogit[p] - mx);
        int s = (int)((apack[p] >> 21) & 0x1FFFF);
        o += wgt * xl2c[(size_t)slot_of[s] * 64 + lane];
    }
    float h = fmaxf(o / den + bias_l, 0.f);
    // MLP head
    int yi = i / rf;
    float y0 = y[2 * yi], y1 = y[2 * yi + 1];
    float t0 = fmaxf(y0 * W0[0] + y1 * W0[2] + b0[0], 0.f);
    float t1 = fmaxf(y0 * W0[1] + y1 * W0[3] + b0[1], 0.f);
    int j = lane & 31;
    float acc = b1[j];
#pragma unroll
    for (int k = 0; k < 64; ++k) acc += __shfl(h, k, 64) * W1[k * 32 + j];
    acc += t0 * W1[64 * 32 + j] + t1 * W1[65 * 32 + j];
    acc = fmaxf(acc, 0.f);
    float res = b2[j];
#pragma unroll
    for (int k = 0; k < 32; ++k) res += __shfl(acc, k, 64) * W2[k * 32 + j];
    if (lane < 32) out[(size_t)r * 32 + j] = res;
}

extern "C" void kernel_launch(void* const* d_in, const int* in_sizes, int n_in,
                              void* d_out, int out_size, void* d_ws,
                              size_t ws_size, hipStream_t stream)
{
    const float* x     = (const float*)d_in[0];
    const float* eattr = (const float*)d_in[1];
    const float* y     = (const float*)d_in[2];
    const float* Wl1 = (const float*)d_in[3],  *bl1 = (const float*)d_in[4];
    const float* Wr1 = (const float*)d_in[5],  *br1 = (const float*)d_in[6];
    const float* We1 = (const float*)d_in[7],  *att1 = (const float*)d_in[8];
    const float* bias1 = (const float*)d_in[9];
    const float* Wl2 = (const float*)d_in[10], *bl2 = (const float*)d_in[11];
    const float* Wr2 = (const float*)d_in[12], *br2 = (const float*)d_in[13];
    const float* We2 = (const float*)d_in[14], *att2 = (const float*)d_in[15];
    const float* bias2 = (const float*)d_in[16];
    const float* W0 = (const float*)d_in[17], *b0 = (const float*)d_in[18];
    const float* W1 = (const float*)d_in[19], *b1 = (const float*)d_in[20];
    const float* W2 = (const float*)d_in[21], *b2 = (const float*)d_in[22];
    const int* eidx = (const int*)d_in[23];
    const int* nidx = (const int*)d_in[24];

    const int N = in_sizes[0] / 128;
    const int E = in_sizes[1] / 32;
    const int NSEL = in_sizes[24];
    const int NGr = in_sizes[2] / 2;
    const int rf = N / NGr;

    const int* src = eidx;
    const int* dst = eidx + E;

    size_t off = 0;
    auto alloc = [&](size_t nb) {
        size_t r = off;
        off += (nb + 255) & ~(size_t)255;
        return r;
    };
    char* ws = (char*)d_ws;
    const int NBW = (N + 31) / 32;

    // ---- zero-init region (one memset) ----
    unsigned* selbits = (unsigned*)(ws + alloc((size_t)NBW * 4));
    unsigned* f1bits  = (unsigned*)(ws + alloc((size_t)NBW * 4));
    int* indeg  = (int*)(ws + alloc((size_t)N * 4));
    int* cursor = (int*)(ws + alloc((size_t)NF1CAP * 4));
    int* ctrs   = (int*)(ws + alloc(256));  // [0]=nf1 [1]=ne1
    size_t zero_bytes = off;
    // ---- rest ----
    int* slot_of = (int*)(ws + alloc((size_t)N * 4));
    int* f1node  = (int*)(ws + alloc((size_t)NF1CAP * 4));
    int* aoffs   = (int*)(ws + alloc((size_t)(NF1CAP + 1) * 4));
    unsigned long long* apack =
        (unsigned long long*)(ws + alloc((size_t)E * 8));
    float* alogit = (float*)(ws + alloc((size_t)E * 4));
    float* mattr  = (float*)(ws + alloc((size_t)NF1CAP * 32 * 4));
    float* xl1  = (float*)(ws + alloc((size_t)N * 64 * 4));
    float* xr1c = (float*)(ws + alloc((size_t)NF1CAP * 64 * 4));
    float* h1c  = (float*)(ws + alloc((size_t)NF1CAP * 64 * 4));
    float* xl2c = (float*)(ws + alloc((size_t)NF1CAP * 64 * 4));
    float* xr2c = (float*)(ws + alloc((size_t)NF1CAP * 64 * 4));
    (void)ws_size;

    int* nf1_p = ctrs + 0;
    int* ne1_p = ctrs + 1;

    hipMemsetAsync(ws, 0, zero_bytes, stream);

    // frontier + compact CSR (packed records)
    mark_sel_kernel<<<(NSEL + 255) / 256, 256, 0, stream>>>(nidx, selbits,
                                                            f1bits, NSEL);
    pass_a_kernel<<<2048, 256, 0, stream>>>(src, dst, selbits, f1bits, indeg, E);
    compact_f1_kernel<<<(N + 255) / 256, 256, 0, stream>>>(f1bits, nf1_p,
                                                           f1node, slot_of, N);
    scan_kernel<<<1, 1024, 0, stream>>>(indeg, f1node, nf1_p, NF1CAP, aoffs,
                                        ne1_p);
    scatter_kernel<<<2048, 256, 0, stream>>>(src, dst, f1bits, slot_of, aoffs,
                                             cursor, apack, E);
    // layer-1 transforms (fused dense-xl + compact-xr)
    gemm_fused_kernel<128><<<2048, 256, 0, stream>>>(x, Wl1, bl1, Wr1, br1,
                                                     f1node, nf1_p, N, 1792,
                                                     xl1, xr1c);
    // layer-1 attention + aggregation
    logits1_kernel<<<4096, 256, 0, stream>>>(ne1_p, apack, eattr, xl1, xr1c,
                                             We1, att1, alogit);
    sc1_kernel<<<4096, 256, 0, stream>>>(nf1_p, f1node, aoffs, apack, eattr,
                                         mattr, xl1, xr1c, We1, att1, alogit,
                                         bias1, h1c);
    // layer-2 transforms (compact over F1)
    gemm2_kernel<<<1024, 256, 0, stream>>>(h1c, Wl2, bl2, Wr2, br2, nf1_p,
                                           xl2c, xr2c);
    // layer-2 attention + aggregation + head at selected nodes
    logits2_kernel<<<NSEL * 4, 256, 0, stream>>>(nidx, slot_of, aoffs, apack,
                                                 eattr, xl2c, xr2c, We2, att2,
                                                 alogit, NSEL);
    tail2_kernel<<<(NSEL + 3) / 4, 256, 0, stream>>>(
        nidx, slot_of, aoffs, apack, mattr, xl2c, xr2c, We2, att2, alogit,
        bias2, y, W0, b0, W1, b1, W2, b2, (float*)d_out, NSEL, rf);
}

// Round 5
// 757.381 us; speedup vs baseline: 1.7035x; 1.0751x over previous
//
#include <hip/hip_runtime.h>

// ---------------------------------------------------------------------------
// GATv2 x2 + MLP head, output at node_idx (1000 rows).
// Frontier-compact pipeline, packed-record CSR + tiled f32 GEMMs:
//   mark sel/F1 bitmaps (+full indeg) -> compact F1 -> scan -> scatter of
//   packed u64 {eid|src|slot} -> tiled GEMMs (dense xl1, compact xr1) ->
//   edge-parallel logits -> merged self-loop+combine (layer1) -> tiled
//   layer2 GEMMs -> per-sel-node sub-wave logits -> merged tail (self-loop +
//   combine + MLP head).
// ---------------------------------------------------------------------------

#define NF1CAP 24576   // cap on |F1| (expected ~15.6k)

__device__ __forceinline__ int getbit(const unsigned* b, int i) {
    return (b[i >> 5] >> (i & 31)) & 1;
}

__global__ __launch_bounds__(256)
void mark_sel_kernel(const int* __restrict__ nidx, unsigned* __restrict__ selbits,
                     unsigned* __restrict__ f1bits, int n)
{
    int t = blockIdx.x * blockDim.x + threadIdx.x;
    if (t < n) {
        int i = nidx[t];
        atomicOr(&selbits[i >> 5], 1u << (i & 31));
        atomicOr(&f1bits[i >> 5], 1u << (i & 31));
    }
}

// full in-degree histogram + mark srcs of edges whose dst is selected
__global__ __launch_bounds__(256)
void pass_a_kernel(const int* __restrict__ src, const int* __restrict__ dst,
                   const unsigned* __restrict__ selbits,
                   unsigned* __restrict__ f1bits, int* __restrict__ indeg, int E)
{
    int E4 = E >> 2;
    for (int i = blockIdx.x * blockDim.x + threadIdx.x; i < E4;
         i += gridDim.x * blockDim.x) {
        int4 d4 = ((const int4*)dst)[i];
        int dd[4] = {d4.x, d4.y, d4.z, d4.w};
#pragma unroll
        for (int j = 0; j < 4; ++j) {
            int d = dd[j];
            atomicAdd(&indeg[d], 1);
            if (getbit(selbits, d)) {
                int s = src[i * 4 + j];
                atomicOr(&f1bits[s >> 5], 1u << (s & 31));
            }
        }
    }
    int t = blockIdx.x * blockDim.x + threadIdx.x;
    if (t < (E & 3)) {
        int e = (E4 << 2) + t;
        int d = dst[e];
        atomicAdd(&indeg[d], 1);
        if (getbit(selbits, d)) {
            int s = src[e];
            atomicOr(&f1bits[s >> 5], 1u << (s & 31));
        }
    }
}

__global__ __launch_bounds__(256)
void compact_f1_kernel(const unsigned* __restrict__ f1bits, int* __restrict__ nf1,
                       int* __restrict__ f1node, int* __restrict__ slot_of, int n)
{
    int i = blockIdx.x * blockDim.x + threadIdx.x;
    if (i >= n) return;
    if (getbit(f1bits, i)) {
        int s = atomicAdd(nf1, 1);   // compiler wave-coalesces count-atomics
        if (s < NF1CAP) { f1node[s] = i; slot_of[i] = s; }
        else slot_of[i] = 0;
    }
}

__global__ __launch_bounds__(1024)
void scan_kernel(const int* __restrict__ indeg, const int* __restrict__ f1node,
                 const int* __restrict__ n_ptr, int cap,
                 int* __restrict__ offs, int* __restrict__ ne_out)
{
    __shared__ int buf[1024];
    int n = *n_ptr; if (n > cap) n = cap;
    int tid = threadIdx.x;
    int chunk = (n + 1023) / 1024;
    int base = tid * chunk;
    int s = 0;
    for (int j = 0; j < chunk; ++j) {
        int idx = base + j;
        if (idx < n) s += indeg[f1node[idx]];
    }
    buf[tid] = s;
    __syncthreads();
    for (int off = 1; off < 1024; off <<= 1) {
        int v = (tid >= off) ? buf[tid - off] : 0;
        __syncthreads();
        buf[tid] += v;
        __syncthreads();
    }
    int run = (tid > 0) ? buf[tid - 1] : 0;
    for (int j = 0; j < chunk; ++j) {
        int idx = base + j;
        if (idx < n) { offs[idx] = run; run += indeg[f1node[idx]]; }
    }
    if (tid == 1023) { offs[n] = buf[1023]; *ne_out = buf[1023]; }
}

// packed record: eid[0:21) | src[21:38) | slot[38:53)
__global__ __launch_bounds__(256)
void scatter_kernel(const int* __restrict__ src, const int* __restrict__ dst,
                    const unsigned* __restrict__ f1bits,
                    const int* __restrict__ slot_of, const int* __restrict__ aoffs,
                    int* __restrict__ cursor,
                    unsigned long long* __restrict__ apack, int E)
{
    int E4 = E >> 2;
    for (int i = blockIdx.x * blockDim.x + threadIdx.x; i < E4;
         i += gridDim.x * blockDim.x) {
        int4 d4 = ((const int4*)dst)[i];
        int dd[4] = {d4.x, d4.y, d4.z, d4.w};
#pragma unroll
        for (int j = 0; j < 4; ++j) {
            int d = dd[j];
            if (!getbit(f1bits, d)) continue;
            int a = slot_of[d];
            int pos = aoffs[a] + atomicAdd(&cursor[a], 1);
            int e = i * 4 + j;
            apack[pos] = (unsigned long long)(unsigned)e
                       | ((unsigned long long)(unsigned)src[e] << 21)
                       | ((unsigned long long)(unsigned)a << 38);
        }
    }
    int t = blockIdx.x * blockDim.x + threadIdx.x;
    if (t < (E & 3)) {
        int e = (E4 << 2) + t;
        int d = dst[e];
        if (getbit(f1bits, d)) {
            int a = slot_of[d];
            int pos = aoffs[a] + atomicAdd(&cursor[a], 1);
            apack[pos] = (unsigned long long)(unsigned)e
                       | ((unsigned long long)(unsigned)src[e] << 21)
                       | ((unsigned long long)(unsigned)a << 38);
        }
    }
}

// Tiled f32 GEMM: out[r][0:64] = X[row(r)][0:K] @ W[K][64] + bias.
// BM=128 rows/block, BK=32, 256 threads, each thread 4 rows x 8 cols.
// A staged transposed in LDS (coalesced global reads, b128 compute reads);
// W staged whole in LDS once. rowlist optional gather; rows fixed or from ptr.
template <int K>
__global__ __launch_bounds__(256)
void gemm_tiled_kernel(const float* __restrict__ X,
                       const float* __restrict__ W, const float* __restrict__ bias,
                       const int* __restrict__ rowlist,
                       const int* __restrict__ nrows_p, int nrows_fixed, int cap,
                       float* __restrict__ out)
{
    constexpr int BM = 128, BK = 32, LDA = BM + 4;
    __shared__ float sW[K * 64];
    __shared__ float sA[BK * LDA];
    int rows = nrows_p ? *nrows_p : nrows_fixed;
    if (rows > cap) rows = cap;
    int base = (int)blockIdx.x * BM;
    if (base >= rows) return;            // uniform per block
    int tid = threadIdx.x;
    for (int t = tid; t < K * 16; t += 256)
        ((float4*)sW)[t] = ((const float4*)W)[t];
    int tx = tid & 7, ty = tid >> 3;
    int c0 = tx * 8;
    float acc[4][8];
#pragma unroll
    for (int i = 0; i < 4; ++i)
#pragma unroll
        for (int j = 0; j < 8; ++j) acc[i][j] = 0.f;

    for (int kb = 0; kb < K; kb += BK) {
        __syncthreads();                 // sA reuse (and W staging, 1st iter)
#pragma unroll
        for (int q = 0; q < 4; ++q) {
            int lin = q * 256 + tid;
            int m = lin >> 3;
            int kk = (lin & 7) * 4;
            int rr = base + m;
            if (rr >= rows) rr = rows - 1;
            int grow = rowlist ? rowlist[rr] : rr;
            float4 v = *(const float4*)&X[(size_t)grow * K + kb + kk];
            sA[(kk + 0) * LDA + m] = v.x;
            sA[(kk + 1) * LDA + m] = v.y;
            sA[(kk + 2) * LDA + m] = v.z;
            sA[(kk + 3) * LDA + m] = v.w;
        }
        __syncthreads();
#pragma unroll
        for (int k = 0; k < BK; ++k) {
            float4 a4 = *(const float4*)&sA[k * LDA + ty * 4];
            float4 w0 = *(const float4*)&sW[(kb + k) * 64 + c0];
            float4 w1 = *(const float4*)&sW[(kb + k) * 64 + c0 + 4];
            float av[4] = {a4.x, a4.y, a4.z, a4.w};
            float wv[8] = {w0.x, w0.y, w0.z, w0.w, w1.x, w1.y, w1.z, w1.w};
#pragma unroll
            for (int i = 0; i < 4; ++i)
#pragma unroll
                for (int j = 0; j < 8; ++j)
                    acc[i][j] += av[i] * wv[j];
        }
    }
    float bv[8];
#pragma unroll
    for (int j = 0; j < 8; ++j) bv[j] = bias[c0 + j];
#pragma unroll
    for (int i = 0; i < 4; ++i) {
        int r = base + ty * 4 + i;
        if (r < rows) {
            float o[8];
#pragma unroll
            for (int j = 0; j < 8; ++j) o[j] = acc[i][j] + bv[j];
            *(float4*)&out[(size_t)r * 64 + c0] = *(float4*)&o[0];
            *(float4*)&out[(size_t)r * 64 + c0 + 4] = *(float4*)&o[4];
        }
    }
}

// edge-parallel layer-1 logits: one wave per CSR position
__global__ __launch_bounds__(256)
void logits1_kernel(const int* __restrict__ ne_ptr,
                    const unsigned long long* __restrict__ apack,
                    const float* __restrict__ eattr, const float* __restrict__ xl,
                    const float* __restrict__ xrc, const float* __restrict__ We,
                    const float* __restrict__ att, float* __restrict__ alogit)
{
    int lane = threadIdx.x & 63;
    int gw = (blockIdx.x * blockDim.x + threadIdx.x) >> 6;
    int nw = (gridDim.x * blockDim.x) >> 6;
    float wec[32];
#pragma unroll
    for (int k = 0; k < 32; ++k) wec[k] = We[k * 64 + lane];
    float att_l = att[lane];
    int n = *ne_ptr;
    for (int p = gw; p < n; p += nw) {
        unsigned long long rec = apack[p];
        int e = (int)(rec & 0x1FFFFF);
        int s = (int)((rec >> 21) & 0x1FFFF);
        int a = (int)((rec >> 38) & 0x7FFF);
        const float4* a4 = (const float4*)(eattr + (size_t)e * 32);
        float emb = 0.f;
#pragma unroll
        for (int q = 0; q < 8; ++q) {
            float4 v = a4[q];
            emb += v.x * wec[4 * q] + v.y * wec[4 * q + 1]
                 + v.z * wec[4 * q + 2] + v.w * wec[4 * q + 3];
        }
        float m = xl[(size_t)s * 64 + lane] + xrc[(size_t)a * 64 + lane] + emb;
        m = (m >= 0.f) ? m : 0.2f * m;
        float pf = m * att_l;
#pragma unroll
        for (int d = 32; d; d >>= 1) pf += __shfl_xor(pf, d, 64);
        if (lane == 0) alogit[p] = pf;
    }
}

// layer-2 logits: 16 sub-waves per selected node over its CSR range
__global__ __launch_bounds__(256)
void logits2_kernel(const int* __restrict__ nidx, const int* __restrict__ slot_of,
                    const int* __restrict__ aoffs,
                    const unsigned long long* __restrict__ apack,
                    const float* __restrict__ eattr, const float* __restrict__ xl2c,
                    const float* __restrict__ xr2c, const float* __restrict__ We,
                    const float* __restrict__ att, float* __restrict__ alogit,
                    int nsel)
{
    int lane = threadIdx.x & 63;
    int w = (blockIdx.x * blockDim.x + threadIdx.x) >> 6;
    int item = w >> 4, sub = w & 15;
    if (item >= nsel) return;
    float wec[32];
#pragma unroll
    for (int k = 0; k < 32; ++k) wec[k] = We[k * 64 + lane];
    float att_l = att[lane];
    int i = nidx[item];
    int a = slot_of[i];
    int beg = aoffs[a], end = aoffs[a + 1];
    float xr_l = xr2c[(size_t)a * 64 + lane];
    for (int p = beg + sub; p < end; p += 16) {
        unsigned long long rec = apack[p];
        int e = (int)(rec & 0x1FFFFF);
        int s = (int)((rec >> 21) & 0x1FFFF);
        const float4* a4 = (const float4*)(eattr + (size_t)e * 32);
        float emb = 0.f;
#pragma unroll
        for (int q = 0; q < 8; ++q) {
            float4 v = a4[q];
            emb += v.x * wec[4 * q] + v.y * wec[4 * q + 1]
                 + v.z * wec[4 * q + 2] + v.w * wec[4 * q + 3];
        }
        float m = xl2c[(size_t)slot_of[s] * 64 + lane] + xr_l + emb;
        m = (m >= 0.f) ? m : 0.2f * m;
        float pf = m * att_l;
#pragma unroll
        for (int d = 32; d; d >>= 1) pf += __shfl_xor(pf, d, 64);
        if (lane == 0) alogit[p] = pf;
    }
}

// layer-1 merged: mean-attr + self-logit + softmax combine -> h1c, mattr
__global__ __launch_bounds__(256)
void sc1_kernel(const int* __restrict__ nf1_p, const int* __restrict__ f1node,
                const int* __restrict__ aoffs,
                const unsigned long long* __restrict__ apack,
                const float* __restrict__ eattr, float* __restrict__ mattr,
                const float* __restrict__ xl1, const float* __restrict__ xr1c,
                const float* __restrict__ We, const float* __restrict__ att,
                const float* __restrict__ alogit, const float* __restrict__ bias,
                float* __restrict__ h1c)
{
    int lane = threadIdx.x & 63, l32 = lane & 31, half = lane >> 5;
    int gw = (blockIdx.x * blockDim.x + threadIdx.x) >> 6;
    int nw = (gridDim.x * blockDim.x) >> 6;
    float wec[32];
#pragma unroll
    for (int k = 0; k < 32; ++k) wec[k] = We[k * 64 + lane];
    float att_l = att[lane];
    float bias_l = bias[lane];
    int n = *nf1_p; if (n > NF1CAP) n = NF1CAP;
    for (int a = gw; a < n; a += nw) {
        int i = f1node[a];
        int beg = aoffs[a], end = aoffs[a + 1], deg = end - beg;
        // mean incoming edge_attr (two edges per iteration)
        float ls = 0.f;
        for (int p = beg + half; p < end; p += 2) {
            int e = (int)(apack[p] & 0x1FFFFF);
            ls += eattr[(size_t)e * 32 + l32];
        }
        ls += __shfl_xor(ls, 32, 64);
        float mean = ls * (1.0f / (float)(deg > 0 ? deg : 1));
        if (lane < 32) mattr[(size_t)a * 32 + lane] = mean;
        // self-loop logit
        float emb = 0.f;
#pragma unroll
        for (int k = 0; k < 32; ++k) emb += __shfl(mean, k, 64) * wec[k];
        float xls = xl1[(size_t)i * 64 + lane];
        float m = xls + xr1c[(size_t)a * 64 + lane] + emb;
        m = (m >= 0.f) ? m : 0.2f * m;
        float pf = m * att_l;
#pragma unroll
        for (int d = 32; d; d >>= 1) pf += __shfl_xor(pf, d, 64);
        float slog = pf;
        // softmax over in-edges + self
        float mx = slog;
        for (int p = beg + lane; p < end; p += 64) mx = fmaxf(mx, alogit[p]);
#pragma unroll
        for (int d = 32; d; d >>= 1) mx = fmaxf(mx, __shfl_xor(mx, d, 64));
        float ps = 0.f;
        for (int p = beg + lane; p < end; p += 64) ps += __expf(alogit[p] - mx);
#pragma unroll
        for (int d = 32; d; d >>= 1) ps += __shfl_xor(ps, d, 64);
        float wself = __expf(slog - mx);
        float den = ps + wself;
        float o = wself * xls;
        for (int p = beg; p < end; ++p) {
            float wgt = __expf(alogit[p] - mx);
            int s = (int)((apack[p] >> 21) & 0x1FFFF);
            o += wgt * xl1[(size_t)s * 64 + lane];
        }
        h1c[(size_t)a * 64 + lane] = fmaxf(o / den + bias_l, 0.f);
    }
}

// layer-2 merged tail per selected row: self-logit + combine + MLP head
__global__ __launch_bounds__(256)
void tail2_kernel(const int* __restrict__ nidx, const int* __restrict__ slot_of,
                  const int* __restrict__ aoffs,
                  const unsigned long long* __restrict__ apack,
                  const float* __restrict__ mattr, const float* __restrict__ xl2c,
                  const float* __restrict__ xr2c, const float* __restrict__ We,
                  const float* __restrict__ att, const float* __restrict__ alogit,
                  const float* __restrict__ bias, const float* __restrict__ y,
                  const float* __restrict__ W0, const float* __restrict__ b0,
                  const float* __restrict__ W1, const float* __restrict__ b1,
                  const float* __restrict__ W2, const float* __restrict__ b2,
                  float* __restrict__ out, int nsel, int rf)
{
    int lane = threadIdx.x & 63;
    int r = (blockIdx.x * blockDim.x + threadIdx.x) >> 6;
    if (r >= nsel) return;
    float wec[32];
#pragma unroll
    for (int k = 0; k < 32; ++k) wec[k] = We[k * 64 + lane];
    float att_l = att[lane];
    float bias_l = bias[lane];
    int i = nidx[r];
    int a = slot_of[i];
    int beg = aoffs[a], end = aoffs[a + 1];
    float mean = mattr[(size_t)a * 32 + (lane & 31)];
    float emb = 0.f;
#pragma unroll
    for (int k = 0; k < 32; ++k) emb += __shfl(mean, k, 64) * wec[k];
    float xls = xl2c[(size_t)a * 64 + lane];
    float m = xls + xr2c[(size_t)a * 64 + lane] + emb;
    m = (m >= 0.f) ? m : 0.2f * m;
    float pf = m * att_l;
#pragma unroll
    for (int d = 32; d; d >>= 1) pf += __shfl_xor(pf, d, 64);
    float slog = pf;
    float mx = slog;
    for (int p = beg + lane; p < end; p += 64) mx = fmaxf(mx, alogit[p]);
#pragma unroll
    for (int d = 32; d; d >>= 1) mx = fmaxf(mx, __shfl_xor(mx, d, 64));
    float ps = 0.f;
    for (int p = beg + lane; p < end; p += 64) ps += __expf(alogit[p] - mx);
#pragma unroll
    for (int d = 32; d; d >>= 1) ps += __shfl_xor(ps, d, 64);
    float wself = __expf(slog - mx);
    float den = ps + wself;
    float o = wself * xls;
    for (int p = beg; p < end; ++p) {
        float wgt = __expf(alogit[p] - mx);
        int s = (int)((apack[p] >> 21) & 0x1FFFF);
        o += wgt * xl2c[(size_t)slot_of[s] * 64 + lane];
    }
    float h = fmaxf(o / den + bias_l, 0.f);
    // MLP head
    int yi = i / rf;
    float y0 = y[2 * yi], y1 = y[2 * yi + 1];
    float t0 = fmaxf(y0 * W0[0] + y1 * W0[2] + b0[0], 0.f);
    float t1 = fmaxf(y0 * W0[1] + y1 * W0[3] + b0[1], 0.f);
    int j = lane & 31;
    float acc = b1[j];
#pragma unroll
    for (int k = 0; k < 64; ++k) acc += __shfl(h, k, 64) * W1[k * 32 + j];
    acc += t0 * W1[64 * 32 + j] + t1 * W1[65 * 32 + j];
    acc = fmaxf(acc, 0.f);
    float res = b2[j];
#pragma unroll
    for (int k = 0; k < 32; ++k) res += __shfl(acc, k, 64) * W2[k * 32 + j];
    if (lane < 32) out[(size_t)r * 32 + j] = res;
}

extern "C" void kernel_launch(void* const* d_in, const int* in_sizes, int n_in,
                              void* d_out, int out_size, void* d_ws,
                              size_t ws_size, hipStream_t stream)
{
    const float* x     = (const float*)d_in[0];
    const float* eattr = (const float*)d_in[1];
    const float* y     = (const float*)d_in[2];
    const float* Wl1 = (const float*)d_in[3],  *bl1 = (const float*)d_in[4];
    const float* Wr1 = (const float*)d_in[5],  *br1 = (const float*)d_in[6];
    const float* We1 = (const float*)d_in[7],  *att1 = (const float*)d_in[8];
    const float* bias1 = (const float*)d_in[9];
    const float* Wl2 = (const float*)d_in[10], *bl2 = (const float*)d_in[11];
    const float* Wr2 = (const float*)d_in[12], *br2 = (const float*)d_in[13];
    const float* We2 = (const float*)d_in[14], *att2 = (const float*)d_in[15];
    const float* bias2 = (const float*)d_in[16];
    const float* W0 = (const float*)d_in[17], *b0 = (const float*)d_in[18];
    const float* W1 = (const float*)d_in[19], *b1 = (const float*)d_in[20];
    const float* W2 = (const float*)d_in[21], *b2 = (const float*)d_in[22];
    const int* eidx = (const int*)d_in[23];
    const int* nidx = (const int*)d_in[24];

    const int N = in_sizes[0] / 128;
    const int E = in_sizes[1] / 32;
    const int NSEL = in_sizes[24];
    const int NGr = in_sizes[2] / 2;
    const int rf = N / NGr;

    const int* src = eidx;
    const int* dst = eidx + E;

    size_t off = 0;
    auto alloc = [&](size_t nb) {
        size_t r = off;
        off += (nb + 255) & ~(size_t)255;
        return r;
    };
    char* ws = (char*)d_ws;
    const int NBW = (N + 31) / 32;

    // ---- zero-init region (one memset) ----
    unsigned* selbits = (unsigned*)(ws + alloc((size_t)NBW * 4));
    unsigned* f1bits  = (unsigned*)(ws + alloc((size_t)NBW * 4));
    int* indeg  = (int*)(ws + alloc((size_t)N * 4));
    int* cursor = (int*)(ws + alloc((size_t)NF1CAP * 4));
    int* ctrs   = (int*)(ws + alloc(256));  // [0]=nf1 [1]=ne1
    size_t zero_bytes = off;
    // ---- rest ----
    int* slot_of = (int*)(ws + alloc((size_t)N * 4));
    int* f1node  = (int*)(ws + alloc((size_t)NF1CAP * 4));
    int* aoffs   = (int*)(ws + alloc((size_t)(NF1CAP + 1) * 4));
    unsigned long long* apack =
        (unsigned long long*)(ws + alloc((size_t)E * 8));
    float* alogit = (float*)(ws + alloc((size_t)E * 4));
    float* mattr  = (float*)(ws + alloc((size_t)NF1CAP * 32 * 4));
    float* xl1  = (float*)(ws + alloc((size_t)N * 64 * 4));
    float* xr1c = (float*)(ws + alloc((size_t)NF1CAP * 64 * 4));
    float* h1c  = (float*)(ws + alloc((size_t)NF1CAP * 64 * 4));
    float* xl2c = (float*)(ws + alloc((size_t)NF1CAP * 64 * 4));
    float* xr2c = (float*)(ws + alloc((size_t)NF1CAP * 64 * 4));
    (void)ws_size;

    int* nf1_p = ctrs + 0;
    int* ne1_p = ctrs + 1;

    hipMemsetAsync(ws, 0, zero_bytes, stream);

    // frontier + compact CSR (packed records)
    mark_sel_kernel<<<(NSEL + 255) / 256, 256, 0, stream>>>(nidx, selbits,
                                                            f1bits, NSEL);
    pass_a_kernel<<<2048, 256, 0, stream>>>(src, dst, selbits, f1bits, indeg, E);
    compact_f1_kernel<<<(N + 255) / 256, 256, 0, stream>>>(f1bits, nf1_p,
                                                           f1node, slot_of, N);
    scan_kernel<<<1, 1024, 0, stream>>>(indeg, f1node, nf1_p, NF1CAP, aoffs,
                                        ne1_p);
    scatter_kernel<<<2048, 256, 0, stream>>>(src, dst, f1bits, slot_of, aoffs,
                                             cursor, apack, E);
    // layer-1 transforms (tiled GEMMs: dense xl1 + compact xr1)
    gemm_tiled_kernel<128><<<(N + 127) / 128, 256, 0, stream>>>(
        x, Wl1, bl1, nullptr, nullptr, N, N, xl1);
    gemm_tiled_kernel<128><<<NF1CAP / 128, 256, 0, stream>>>(
        x, Wr1, br1, f1node, nf1_p, 0, NF1CAP, xr1c);
    // layer-1 attention + aggregation
    logits1_kernel<<<4096, 256, 0, stream>>>(ne1_p, apack, eattr, xl1, xr1c,
                                             We1, att1, alogit);
    sc1_kernel<<<4096, 256, 0, stream>>>(nf1_p, f1node, aoffs, apack, eattr,
                                         mattr, xl1, xr1c, We1, att1, alogit,
                                         bias1, h1c);
    // layer-2 transforms (compact over F1)
    gemm_tiled_kernel<64><<<NF1CAP / 128, 256, 0, stream>>>(
        h1c, Wl2, bl2, nullptr, nf1_p, 0, NF1CAP, xl2c);
    gemm_tiled_kernel<64><<<NF1CAP / 128, 256, 0, stream>>>(
        h1c, Wr2, br2, nullptr, nf1_p, 0, NF1CAP, xr2c);
    // layer-2 attention + aggregation + head at selected nodes
    logits2_kernel<<<NSEL * 4, 256, 0, stream>>>(nidx, slot_of, aoffs, apack,
                                                 eattr, xl2c, xr2c, We2, att2,
                                                 alogit, NSEL);
    tail2_kernel<<<(NSEL + 3) / 4, 256, 0, stream>>>(
        nidx, slot_of, aoffs, apack, mattr, xl2c, xr2c, We2, att2, alogit,
        bias2, y, W0, b0, W1, b1, W2, b2, (float*)d_out, NSEL, rf);
}

// Round 7
// 688.970 us; speedup vs baseline: 1.8727x; 1.0993x over previous
//
#include <hip/hip_runtime.h>

// ---------------------------------------------------------------------------
// GATv2 x2 + MLP head, output at node_idx (1000 rows).
// Frontier-compact pipeline, packed-record CSR + tiled f32 GEMMs +
// block-tile edge logits (LDS-staged edge attrs, ILP'd row loads).
// ---------------------------------------------------------------------------

#define NF1CAP 24576   // cap on |F1| (expected ~15.6k)

__device__ __forceinline__ int getbit(const unsigned* b, int i) {
    return (b[i >> 5] >> (i & 31)) & 1;
}

__global__ __launch_bounds__(256)
void mark_sel_kernel(const int* __restrict__ nidx, unsigned* __restrict__ selbits,
                     unsigned* __restrict__ f1bits, int n)
{
    int t = blockIdx.x * blockDim.x + threadIdx.x;
    if (t < n) {
        int i = nidx[t];
        atomicOr(&selbits[i >> 5], 1u << (i & 31));
        atomicOr(&f1bits[i >> 5], 1u << (i & 31));
    }
}

// full in-degree histogram + mark srcs of edges whose dst is selected
__global__ __launch_bounds__(256)
void pass_a_kernel(const int* __restrict__ src, const int* __restrict__ dst,
                   const unsigned* __restrict__ selbits,
                   unsigned* __restrict__ f1bits, int* __restrict__ indeg, int E)
{
    int E4 = E >> 2;
    for (int i = blockIdx.x * blockDim.x + threadIdx.x; i < E4;
         i += gridDim.x * blockDim.x) {
        int4 d4 = ((const int4*)dst)[i];
        int dd[4] = {d4.x, d4.y, d4.z, d4.w};
#pragma unroll
        for (int j = 0; j < 4; ++j) {
            int d = dd[j];
            atomicAdd(&indeg[d], 1);
            if (getbit(selbits, d)) {
                int s = src[i * 4 + j];
                atomicOr(&f1bits[s >> 5], 1u << (s & 31));
            }
        }
    }
    int t = blockIdx.x * blockDim.x + threadIdx.x;
    if (t < (E & 3)) {
        int e = (E4 << 2) + t;
        int d = dst[e];
        atomicAdd(&indeg[d], 1);
        if (getbit(selbits, d)) {
            int s = src[e];
            atomicOr(&f1bits[s >> 5], 1u << (s & 31));
        }
    }
}

__global__ __launch_bounds__(256)
void compact_f1_kernel(const unsigned* __restrict__ f1bits, int* __restrict__ nf1,
                       int* __restrict__ f1node, int* __restrict__ slot_of, int n)
{
    int i = blockIdx.x * blockDim.x + threadIdx.x;
    if (i >= n) return;
    if (getbit(f1bits, i)) {
        int s = atomicAdd(nf1, 1);   // compiler wave-coalesces count-atomics
        if (s < NF1CAP) { f1node[s] = i; slot_of[i] = s; }
        else slot_of[i] = 0;
    }
}

__global__ __launch_bounds__(1024)
void scan_kernel(const int* __restrict__ indeg, const int* __restrict__ f1node,
                 const int* __restrict__ n_ptr, int cap,
                 int* __restrict__ offs, int* __restrict__ ne_out)
{
    __shared__ int buf[1024];
    int n = *n_ptr; if (n > cap) n = cap;
    int tid = threadIdx.x;
    int chunk = (n + 1023) / 1024;
    int base = tid * chunk;
    int s = 0;
    for (int j = 0; j < chunk; ++j) {
        int idx = base + j;
        if (idx < n) s += indeg[f1node[idx]];
    }
    buf[tid] = s;
    __syncthreads();
    for (int off = 1; off < 1024; off <<= 1) {
        int v = (tid >= off) ? buf[tid - off] : 0;
        __syncthreads();
        buf[tid] += v;
        __syncthreads();
    }
    int run = (tid > 0) ? buf[tid - 1] : 0;
    for (int j = 0; j < chunk; ++j) {
        int idx = base + j;
        if (idx < n) { offs[idx] = run; run += indeg[f1node[idx]]; }
    }
    if (tid == 1023) { offs[n] = buf[1023]; *ne_out = buf[1023]; }
}

// packed record: eid[0:21) | src[21:38) | slot[38:53)
__global__ __launch_bounds__(256)
void scatter_kernel(const int* __restrict__ src, const int* __restrict__ dst,
                    const unsigned* __restrict__ f1bits,
                    const int* __restrict__ slot_of, const int* __restrict__ aoffs,
                    int* __restrict__ cursor,
                    unsigned long long* __restrict__ apack, int E)
{
    int E4 = E >> 2;
    for (int i = blockIdx.x * blockDim.x + threadIdx.x; i < E4;
         i += gridDim.x * blockDim.x) {
        int4 d4 = ((const int4*)dst)[i];
        int dd[4] = {d4.x, d4.y, d4.z, d4.w};
#pragma unroll
        for (int j = 0; j < 4; ++j) {
            int d = dd[j];
            if (!getbit(f1bits, d)) continue;
            int a = slot_of[d];
            int pos = aoffs[a] + atomicAdd(&cursor[a], 1);
            int e = i * 4 + j;
            apack[pos] = (unsigned long long)(unsigned)e
                       | ((unsigned long long)(unsigned)src[e] << 21)
                       | ((unsigned long long)(unsigned)a << 38);
        }
    }
    int t = blockIdx.x * blockDim.x + threadIdx.x;
    if (t < (E & 3)) {
        int e = (E4 << 2) + t;
        int d = dst[e];
        if (getbit(f1bits, d)) {
            int a = slot_of[d];
            int pos = aoffs[a] + atomicAdd(&cursor[a], 1);
            apack[pos] = (unsigned long long)(unsigned)e
                       | ((unsigned long long)(unsigned)src[e] << 21)
                       | ((unsigned long long)(unsigned)a << 38);
        }
    }
}

// Tiled f32 GEMM: out[r][0:64] = X[row(r)][0:K] @ W[K][64] + bias.
template <int K>
__global__ __launch_bounds__(256)
void gemm_tiled_kernel(const float* __restrict__ X,
                       const float* __restrict__ W, const float* __restrict__ bias,
                       const int* __restrict__ rowlist,
                       const int* __restrict__ nrows_p, int nrows_fixed, int cap,
                       float* __restrict__ out)
{
    constexpr int BM = 128, BK = 32, LDA = BM + 4;
    __shared__ float sW[K * 64];
    __shared__ float sA[BK * LDA];
    int rows = nrows_p ? *nrows_p : nrows_fixed;
    if (rows > cap) rows = cap;
    int base = (int)blockIdx.x * BM;
    if (base >= rows) return;            // uniform per block
    int tid = threadIdx.x;
    for (int t = tid; t < K * 16; t += 256)
        ((float4*)sW)[t] = ((const float4*)W)[t];
    int tx = tid & 7, ty = tid >> 3;
    int c0 = tx * 8;
    float acc[4][8];
#pragma unroll
    for (int i = 0; i < 4; ++i)
#pragma unroll
        for (int j = 0; j < 8; ++j) acc[i][j] = 0.f;

    for (int kb = 0; kb < K; kb += BK) {
        __syncthreads();                 // sA reuse (and W staging, 1st iter)
#pragma unroll
        for (int q = 0; q < 4; ++q) {
            int lin = q * 256 + tid;
            int m = lin >> 3;
            int kk = (lin & 7) * 4;
            int rr = base + m;
            if (rr >= rows) rr = rows - 1;
            int grow = rowlist ? rowlist[rr] : rr;
            float4 v = *(const float4*)&X[(size_t)grow * K + kb + kk];
            sA[(kk + 0) * LDA + m] = v.x;
            sA[(kk + 1) * LDA + m] = v.y;
            sA[(kk + 2) * LDA + m] = v.z;
            sA[(kk + 3) * LDA + m] = v.w;
        }
        __syncthreads();
#pragma unroll
        for (int k = 0; k < BK; ++k) {
            float4 a4 = *(const float4*)&sA[k * LDA + ty * 4];
            float4 w0 = *(const float4*)&sW[(kb + k) * 64 + c0];
            float4 w1 = *(const float4*)&sW[(kb + k) * 64 + c0 + 4];
            float av[4] = {a4.x, a4.y, a4.z, a4.w};
            float wv[8] = {w0.x, w0.y, w0.z, w0.w, w1.x, w1.y, w1.z, w1.w};
#pragma unroll
            for (int i = 0; i < 4; ++i)
#pragma unroll
                for (int j = 0; j < 8; ++j)
                    acc[i][j] += av[i] * wv[j];
        }
    }
    float bv[8];
#pragma unroll
    for (int j = 0; j < 8; ++j) bv[j] = bias[c0 + j];
#pragma unroll
    for (int i = 0; i < 4; ++i) {
        int r = base + ty * 4 + i;
        if (r < rows) {
            float o[8];
#pragma unroll
            for (int j = 0; j < 8; ++j) o[j] = acc[i][j] + bv[j];
            *(float4*)&out[(size_t)r * 64 + c0] = *(float4*)&o[0];
            *(float4*)&out[(size_t)r * 64 + c0 + 4] = *(float4*)&o[4];
        }
    }
}

// Block-tile layer-1 logits: 64 edges per block (256 thr), attr rows staged
// coalesced in LDS; each wave owns 16 edges; 4-edge chunks for load ILP.
__global__ __launch_bounds__(256)
void logits1_kernel(const int* __restrict__ ne_ptr,
                    const unsigned long long* __restrict__ apack,
                    const float* __restrict__ eattr, const float* __restrict__ xl,
                    const float* __restrict__ xrc, const float* __restrict__ We,
                    const float* __restrict__ att, float* __restrict__ alogit)
{
    constexpr int LDE = 36;              // padded row stride (floats)
    __shared__ float sAttr[64 * LDE];
    int tid = threadIdx.x;
    int lane = tid & 63, w = tid >> 6;
    float wec[32];
#pragma unroll
    for (int k = 0; k < 32; ++k) wec[k] = We[k * 64 + lane];
    float att_l = att[lane];
    int n = *ne_ptr;
    int ntiles = (n + 63) >> 6;
    for (int tile = blockIdx.x; tile < ntiles; tile += gridDim.x) {
        int base = tile << 6;
        __syncthreads();                 // protect sAttr reuse
        // stage 64 attr rows: 512 float4 loads, 2 per thread, coalesced
#pragma unroll
        for (int q = 0; q < 2; ++q) {
            int lin = q * 256 + tid;
            int el = lin >> 3, quad = lin & 7;
            int p = base + el; if (p >= n) p = n - 1;
            int e = (int)(apack[p] & 0x1FFFFF);
            float4 v = ((const float4*)(eattr + (size_t)e * 32))[quad];
            *(float4*)&sAttr[el * LDE + quad * 4] = v;
        }
        __syncthreads();
        float res = 0.f;
#pragma unroll
        for (int j0 = 0; j0 < 16; j0 += 4) {
            float xlv[4], xrv[4];
#pragma unroll
            for (int u = 0; u < 4; ++u) {
                int p = base + w * 16 + j0 + u; if (p >= n) p = n - 1;
                unsigned long long rec = apack[p];
                int s = (int)((rec >> 21) & 0x1FFFF);
                int a = (int)((rec >> 38) & 0x7FFF);
                xlv[u] = xl[(size_t)s * 64 + lane];
                xrv[u] = xrc[(size_t)a * 64 + lane];
            }
#pragma unroll
            for (int u = 0; u < 4; ++u) {
                int el = w * 16 + j0 + u;
                const float* ar = &sAttr[el * LDE];
                float emb = 0.f;
#pragma unroll
                for (int k = 0; k < 32; ++k) emb += ar[k] * wec[k];
                float m = xlv[u] + xrv[u] + emb;
                m = (m >= 0.f) ? m : 0.2f * m;
                float pf = m * att_l;
#pragma unroll
                for (int d = 32; d; d >>= 1) pf += __shfl_xor(pf, d, 64);
                res = (lane == j0 + u) ? pf : res;
            }
        }
        int li = base + w * 16 + lane;
        if (lane < 16 && li < n) alogit[li] = res;
    }
}

// layer-2 logits: 16 sub-waves per selected node over its CSR range
__global__ __launch_bounds__(256)
void logits2_kernel(const int* __restrict__ nidx, const int* __restrict__ slot_of,
                    const int* __restrict__ aoffs,
                    const unsigned long long* __restrict__ apack,
                    const float* __restrict__ eattr, const float* __restrict__ xl2c,
                    const float* __restrict__ xr2c, const float* __restrict__ We,
                    const float* __restrict__ att, float* __restrict__ alogit,
                    int nsel)
{
    int lane = threadIdx.x & 63;
    int w = (blockIdx.x * blockDim.x + threadIdx.x) >> 6;
    int item = w >> 4, sub = w & 15;
    if (item >= nsel) return;
    float wec[32];
#pragma unroll
    for (int k = 0; k < 32; ++k) wec[k] = We[k * 64 + lane];
    float att_l = att[lane];
    int i = nidx[item];
    int a = slot_of[i];
    int beg = aoffs[a], end = aoffs[a + 1];
    float xr_l = xr2c[(size_t)a * 64 + lane];
    for (int p = beg + sub; p < end; p += 16) {
        unsigned long long rec = apack[p];
        int e = (int)(rec & 0x1FFFFF);
        int s = (int)((rec >> 21) & 0x1FFFF);
        const float4* a4 = (const float4*)(eattr + (size_t)e * 32);
        float emb = 0.f;
#pragma unroll
        for (int q = 0; q < 8; ++q) {
            float4 v = a4[q];
            emb += v.x * wec[4 * q] + v.y * wec[4 * q + 1]
                 + v.z * wec[4 * q + 2] + v.w * wec[4 * q + 3];
        }
        float m = xl2c[(size_t)slot_of[s] * 64 + lane] + xr_l + emb;
        m = (m >= 0.f) ? m : 0.2f * m;
        float pf = m * att_l;
#pragma unroll
        for (int d = 32; d; d >>= 1) pf += __shfl_xor(pf, d, 64);
        if (lane == 0) alogit[p] = pf;
    }
}

// layer-1 merged: mean-attr + self-logit + softmax combine -> h1c, mattr
__global__ __launch_bounds__(256)
void sc1_kernel(const int* __restrict__ nf1_p, const int* __restrict__ f1node,
                const int* __restrict__ aoffs,
                const unsigned long long* __restrict__ apack,
                const float* __restrict__ eattr, float* __restrict__ mattr,
                const float* __restrict__ xl1, const float* __restrict__ xr1c,
                const float* __restrict__ We, const float* __restrict__ att,
                const float* __restrict__ alogit, const float* __restrict__ bias,
                float* __restrict__ h1c)
{
    int lane = threadIdx.x & 63, l32 = lane & 31, half = lane >> 5;
    int gw = (blockIdx.x * blockDim.x + threadIdx.x) >> 6;
    int nw = (gridDim.x * blockDim.x) >> 6;
    float wec[32];
#pragma unroll
    for (int k = 0; k < 32; ++k) wec[k] = We[k * 64 + lane];
    float att_l = att[lane];
    float bias_l = bias[lane];
    int n = *nf1_p; if (n > NF1CAP) n = NF1CAP;
    for (int a = gw; a < n; a += nw) {
        int i = f1node[a];
        int beg = aoffs[a], end = aoffs[a + 1], deg = end - beg;
        // mean incoming edge_attr (two edges per iteration)
        float ls = 0.f;
        for (int p = beg + half; p < end; p += 2) {
            int e = (int)(apack[p] & 0x1FFFFF);
            ls += eattr[(size_t)e * 32 + l32];
        }
        ls += __shfl_xor(ls, 32, 64);
        float mean = ls * (1.0f / (float)(deg > 0 ? deg : 1));
        if (lane < 32) mattr[(size_t)a * 32 + lane] = mean;
        // self-loop logit
        float emb = 0.f;
#pragma unroll
        for (int k = 0; k < 32; ++k) emb += __shfl(mean, k, 64) * wec[k];
        float xls = xl1[(size_t)i * 64 + lane];
        float m = xls + xr1c[(size_t)a * 64 + lane] + emb;
        m = (m >= 0.f) ? m : 0.2f * m;
        float pf = m * att_l;
#pragma unroll
        for (int d = 32; d; d >>= 1) pf += __shfl_xor(pf, d, 64);
        float slog = pf;
        // softmax over in-edges + self
        float mx = slog;
        for (int p = beg + lane; p < end; p += 64) mx = fmaxf(mx, alogit[p]);
#pragma unroll
        for (int d = 32; d; d >>= 1) mx = fmaxf(mx, __shfl_xor(mx, d, 64));
        float ps = 0.f;
        for (int p = beg + lane; p < end; p += 64) ps += __expf(alogit[p] - mx);
#pragma unroll
        for (int d = 32; d; d >>= 1) ps += __shfl_xor(ps, d, 64);
        float wself = __expf(slog - mx);
        float den = ps + wself;
        // weighted sum, 2-way unrolled with independent partials
        float o0 = wself * xls, o1 = 0.f;
        int p = beg;
        for (; p + 2 <= end; p += 2) {
            unsigned long long r0 = apack[p], r1 = apack[p + 1];
            float w0 = __expf(alogit[p] - mx);
            float w1 = __expf(alogit[p + 1] - mx);
            int s0 = (int)((r0 >> 21) & 0x1FFFF);
            int s1 = (int)((r1 >> 21) & 0x1FFFF);
            o0 += w0 * xl1[(size_t)s0 * 64 + lane];
            o1 += w1 * xl1[(size_t)s1 * 64 + lane];
        }
        if (p < end) {
            float wgt = __expf(alogit[p] - mx);
            int s = (int)((apack[p] >> 21) & 0x1FFFF);
            o0 += wgt * xl1[(size_t)s * 64 + lane];
        }
        h1c[(size_t)a * 64 + lane] = fmaxf((o0 + o1) / den + bias_l, 0.f);
    }
}

// layer-2 merged tail per selected row: self-logit + combine + MLP head
__global__ __launch_bounds__(256)
void tail2_kernel(const int* __restrict__ nidx, const int* __restrict__ slot_of,
                  const int* __restrict__ aoffs,
                  const unsigned long long* __restrict__ apack,
                  const float* __restrict__ mattr, const float* __restrict__ xl2c,
                  const float* __restrict__ xr2c, const float* __restrict__ We,
                  const float* __restrict__ att, const float* __restrict__ alogit,
                  const float* __restrict__ bias, const float* __restrict__ y,
                  const float* __restrict__ W0, const float* __restrict__ b0,
                  const float* __restrict__ W1, const float* __restrict__ b1,
                  const float* __restrict__ W2, const float* __restrict__ b2,
                  float* __restrict__ out, int nsel, int rf)
{
    int lane = threadIdx.x & 63;
    int r = (blockIdx.x * blockDim.x + threadIdx.x) >> 6;
    if (r >= nsel) return;
    float wec[32];
#pragma unroll
    for (int k = 0; k < 32; ++k) wec[k] = We[k * 64 + lane];
    float att_l = att[lane];
    float bias_l = bias[lane];
    int i = nidx[r];
    int a = slot_of[i];
    int beg = aoffs[a], end = aoffs[a + 1];
    float mean = mattr[(size_t)a * 32 + (lane & 31)];
    float emb = 0.f;
#pragma unroll
    for (int k = 0; k < 32; ++k) emb += __shfl(mean, k, 64) * wec[k];
    float xls = xl2c[(size_t)a * 64 + lane];
    float m = xls + xr2c[(size_t)a * 64 + lane] + emb;
    m = (m >= 0.f) ? m : 0.2f * m;
    float pf = m * att_l;
#pragma unroll
    for (int d = 32; d; d >>= 1) pf += __shfl_xor(pf, d, 64);
    float slog = pf;
    float mx = slog;
    for (int p = beg + lane; p < end; p += 64) mx = fmaxf(mx, alogit[p]);
#pragma unroll
    for (int d = 32; d; d >>= 1) mx = fmaxf(mx, __shfl_xor(mx, d, 64));
    float ps = 0.f;
    for (int p = beg + lane; p < end; p += 64) ps += __expf(alogit[p] - mx);
#pragma unroll
    for (int d = 32; d; d >>= 1) ps += __shfl_xor(ps, d, 64);
    float wself = __expf(slog - mx);
    float den = ps + wself;
    float o = wself * xls;
    for (int p = beg; p < end; ++p) {
        float wgt = __expf(alogit[p] - mx);
        int s = (int)((apack[p] >> 21) & 0x1FFFF);
        o += wgt * xl2c[(size_t)slot_of[s] * 64 + lane];
    }
    float h = fmaxf(o / den + bias_l, 0.f);
    // MLP head
    int yi = i / rf;
    float y0 = y[2 * yi], y1 = y[2 * yi + 1];
    float t0 = fmaxf(y0 * W0[0] + y1 * W0[2] + b0[0], 0.f);
    float t1 = fmaxf(y0 * W0[1] + y1 * W0[3] + b0[1], 0.f);
    int j = lane & 31;
    float acc = b1[j];
#pragma unroll
    for (int k = 0; k < 64; ++k) acc += __shfl(h, k, 64) * W1[k * 32 + j];
    acc += t0 * W1[64 * 32 + j] + t1 * W1[65 * 32 + j];
    acc = fmaxf(acc, 0.f);
    float res = b2[j];
#pragma unroll
    for (int k = 0; k < 32; ++k) res += __shfl(acc, k, 64) * W2[k * 32 + j];
    if (lane < 32) out[(size_t)r * 32 + j] = res;
}

extern "C" void kernel_launch(void* const* d_in, const int* in_sizes, int n_in,
                              void* d_out, int out_size, void* d_ws,
                              size_t ws_size, hipStream_t stream)
{
    const float* x     = (const float*)d_in[0];
    const float* eattr = (const float*)d_in[1];
    const float* y     = (const float*)d_in[2];
    const float* Wl1 = (const float*)d_in[3],  *bl1 = (const float*)d_in[4];
    const float* Wr1 = (const float*)d_in[5],  *br1 = (const float*)d_in[6];
    const float* We1 = (const float*)d_in[7],  *att1 = (const float*)d_in[8];
    const float* bias1 = (const float*)d_in[9];
    const float* Wl2 = (const float*)d_in[10], *bl2 = (const float*)d_in[11];
    const float* Wr2 = (const float*)d_in[12], *br2 = (const float*)d_in[13];
    const float* We2 = (const float*)d_in[14], *att2 = (const float*)d_in[15];
    const float* bias2 = (const float*)d_in[16];
    const float* W0 = (const float*)d_in[17], *b0 = (const float*)d_in[18];
    const float* W1 = (const float*)d_in[19], *b1 = (const float*)d_in[20];
    const float* W2 = (const float*)d_in[21], *b2 = (const float*)d_in[22];
    const int* eidx = (const int*)d_in[23];
    const int* nidx = (const int*)d_in[24];

    const int N = in_sizes[0] / 128;
    const int E = in_sizes[1] / 32;
    const int NSEL = in_sizes[24];
    const int NGr = in_sizes[2] / 2;
    const int rf = N / NGr;

    const int* src = eidx;
    const int* dst = eidx + E;

    size_t off = 0;
    auto alloc = [&](size_t nb) {
        size_t r = off;
        off += (nb + 255) & ~(size_t)255;
        return r;
    };
    char* ws = (char*)d_ws;
    const int NBW = (N + 31) / 32;

    // ---- zero-init region (one memset) ----
    unsigned* selbits = (unsigned*)(ws + alloc((size_t)NBW * 4));
    unsigned* f1bits  = (unsigned*)(ws + alloc((size_t)NBW * 4));
    int* indeg  = (int*)(ws + alloc((size_t)N * 4));
    int* cursor = (int*)(ws + alloc((size_t)NF1CAP * 4));
    int* ctrs   = (int*)(ws + alloc(256));  // [0]=nf1 [1]=ne1
    size_t zero_bytes = off;
    // ---- rest ----
    int* slot_of = (int*)(ws + alloc((size_t)N * 4));
    int* f1node  = (int*)(ws + alloc((size_t)NF1CAP * 4));
    int* aoffs   = (int*)(ws + alloc((size_t)(NF1CAP + 1) * 4));
    unsigned long long* apack =
        (unsigned long long*)(ws + alloc((size_t)E * 8));
    float* alogit = (float*)(ws + alloc((size_t)E * 4));
    float* mattr  = (float*)(ws + alloc((size_t)NF1CAP * 32 * 4));
    float* xl1  = (float*)(ws + alloc((size_t)N * 64 * 4));
    float* xr1c = (float*)(ws + alloc((size_t)NF1CAP * 64 * 4));
    float* h1c  = (float*)(ws + alloc((size_t)NF1CAP * 64 * 4));
    float* xl2c = (float*)(ws + alloc((size_t)NF1CAP * 64 * 4));
    float* xr2c = (float*)(ws + alloc((size_t)NF1CAP * 64 * 4));
    (void)ws_size;

    int* nf1_p = ctrs + 0;
    int* ne1_p = ctrs + 1;

    hipMemsetAsync(ws, 0, zero_bytes, stream);

    // frontier + compact CSR (packed records)
    mark_sel_kernel<<<(NSEL + 255) / 256, 256, 0, stream>>>(nidx, selbits,
                                                            f1bits, NSEL);
    pass_a_kernel<<<2048, 256, 0, stream>>>(src, dst, selbits, f1bits, indeg, E);
    compact_f1_kernel<<<(N + 255) / 256, 256, 0, stream>>>(f1bits, nf1_p,
                                                           f1node, slot_of, N);
    scan_kernel<<<1, 1024, 0, stream>>>(indeg, f1node, nf1_p, NF1CAP, aoffs,
                                        ne1_p);
    scatter_kernel<<<2048, 256, 0, stream>>>(src, dst, f1bits, slot_of, aoffs,
                                             cursor, apack, E);
    // layer-1 transforms (tiled GEMMs: dense xl1 + compact xr1)
    gemm_tiled_kernel<128><<<(N + 127) / 128, 256, 0, stream>>>(
        x, Wl1, bl1, nullptr, nullptr, N, N, xl1);
    gemm_tiled_kernel<128><<<NF1CAP / 128, 256, 0, stream>>>(
        x, Wr1, br1, f1node, nf1_p, 0, NF1CAP, xr1c);
    // layer-1 attention + aggregation
    logits1_kernel<<<2048, 256, 0, stream>>>(ne1_p, apack, eattr, xl1, xr1c,
                                             We1, att1, alogit);
    sc1_kernel<<<4096, 256, 0, stream>>>(nf1_p, f1node, aoffs, apack, eattr,
                                         mattr, xl1, xr1c, We1, att1, alogit,
                                         bias1, h1c);
    // layer-2 transforms (compact over F1)
    gemm_tiled_kernel<64><<<NF1CAP / 128, 256, 0, stream>>>(
        h1c, Wl2, bl2, nullptr, nf1_p, 0, NF1CAP, xl2c);
    gemm_tiled_kernel<64><<<NF1CAP / 128, 256, 0, stream>>>(
        h1c, Wr2, br2, nullptr, nf1_p, 0, NF1CAP, xr2c);
    // layer-2 attention + aggregation + head at selected nodes
    logits2_kernel<<<NSEL * 4, 256, 0, stream>>>(nidx, slot_of, aoffs, apack,
                                                 eattr, xl2c, xr2c, We2, att2,
                                                 alogit, NSEL);
    tail2_kernel<<<(NSEL + 3) / 4, 256, 0, stream>>>(
        nidx, slot_of, aoffs, apack, mattr, xl2c, xr2c, We2, att2, alogit,
        bias2, y, W0, b0, W1, b1, W2, b2, (float*)d_out, NSEL, rf);
}

// Round 8
// 670.500 us; speedup vs baseline: 1.9242x; 1.0275x over previous
//
#include <hip/hip_runtime.h>

// ---------------------------------------------------------------------------
// GATv2 x2 + MLP head, output at node_idx (1000 rows).
// Frontier-compact pipeline, packed-record CSR, tiled f32 GEMMs, and fully
// fused per-node aggregation blocks (stage attrs once in LDS -> logits +
// self-loop mean + online softmax + combine [+ MLP head for layer 2]).
// 10 dispatches total.
// ---------------------------------------------------------------------------

#define NF1CAP 24576   // cap on |F1| (expected ~15.6k)

__device__ __forceinline__ int getbit(const unsigned* b, int i) {
    return (b[i >> 5] >> (i & 31)) & 1;
}

__global__ __launch_bounds__(256)
void mark_sel_kernel(const int* __restrict__ nidx, unsigned* __restrict__ selbits,
                     unsigned* __restrict__ f1bits, int n)
{
    int t = blockIdx.x * blockDim.x + threadIdx.x;
    if (t < n) {
        int i = nidx[t];
        atomicOr(&selbits[i >> 5], 1u << (i & 31));
        atomicOr(&f1bits[i >> 5], 1u << (i & 31));
    }
}

// full in-degree histogram + mark srcs of edges whose dst is selected
__global__ __launch_bounds__(256)
void pass_a_kernel(const int* __restrict__ src, const int* __restrict__ dst,
                   const unsigned* __restrict__ selbits,
                   unsigned* __restrict__ f1bits, int* __restrict__ indeg, int E)
{
    int E4 = E >> 2;
    for (int i = blockIdx.x * blockDim.x + threadIdx.x; i < E4;
         i += gridDim.x * blockDim.x) {
        int4 d4 = ((const int4*)dst)[i];
        int dd[4] = {d4.x, d4.y, d4.z, d4.w};
#pragma unroll
        for (int j = 0; j < 4; ++j) {
            int d = dd[j];
            atomicAdd(&indeg[d], 1);
            if (getbit(selbits, d)) {
                int s = src[i * 4 + j];
                atomicOr(&f1bits[s >> 5], 1u << (s & 31));
            }
        }
    }
    int t = blockIdx.x * blockDim.x + threadIdx.x;
    if (t < (E & 3)) {
        int e = (E4 << 2) + t;
        int d = dst[e];
        atomicAdd(&indeg[d], 1);
        if (getbit(selbits, d)) {
            int s = src[e];
            atomicOr(&f1bits[s >> 5], 1u << (s & 31));
        }
    }
}

__global__ __launch_bounds__(256)
void compact_f1_kernel(const unsigned* __restrict__ f1bits, int* __restrict__ nf1,
                       int* __restrict__ f1node, int* __restrict__ slot_of, int n)
{
    int i = blockIdx.x * blockDim.x + threadIdx.x;
    if (i >= n) return;
    if (getbit(f1bits, i)) {
        int s = atomicAdd(nf1, 1);
        if (s < NF1CAP) { f1node[s] = i; slot_of[i] = s; }
        else slot_of[i] = 0;
    }
}

__global__ __launch_bounds__(1024)
void scan_kernel(const int* __restrict__ indeg, const int* __restrict__ f1node,
                 const int* __restrict__ n_ptr, int cap,
                 int* __restrict__ offs, int* __restrict__ ne_out)
{
    __shared__ int buf[1024];
    int n = *n_ptr; if (n > cap) n = cap;
    int tid = threadIdx.x;
    int chunk = (n + 1023) / 1024;
    int base = tid * chunk;
    int s = 0;
    for (int j = 0; j < chunk; ++j) {
        int idx = base + j;
        if (idx < n) s += indeg[f1node[idx]];
    }
    buf[tid] = s;
    __syncthreads();
    for (int off = 1; off < 1024; off <<= 1) {
        int v = (tid >= off) ? buf[tid - off] : 0;
        __syncthreads();
        buf[tid] += v;
        __syncthreads();
    }
    int run = (tid > 0) ? buf[tid - 1] : 0;
    for (int j = 0; j < chunk; ++j) {
        int idx = base + j;
        if (idx < n) { offs[idx] = run; run += indeg[f1node[idx]]; }
    }
    if (tid == 1023) { offs[n] = buf[1023]; *ne_out = buf[1023]; }
}

// packed record: eid[0:21) | src[21:38) | slot[38:53)
__global__ __launch_bounds__(256)
void scatter_kernel(const int* __restrict__ src, const int* __restrict__ dst,
                    const unsigned* __restrict__ f1bits,
                    const int* __restrict__ slot_of, const int* __restrict__ aoffs,
                    int* __restrict__ cursor,
                    unsigned long long* __restrict__ apack, int E)
{
    int E4 = E >> 2;
    for (int i = blockIdx.x * blockDim.x + threadIdx.x; i < E4;
         i += gridDim.x * blockDim.x) {
        int4 d4 = ((const int4*)dst)[i];
        int dd[4] = {d4.x, d4.y, d4.z, d4.w};
#pragma unroll
        for (int j = 0; j < 4; ++j) {
            int d = dd[j];
            if (!getbit(f1bits, d)) continue;
            int a = slot_of[d];
            int pos = aoffs[a] + atomicAdd(&cursor[a], 1);
            int e = i * 4 + j;
            apack[pos] = (unsigned long long)(unsigned)e
                       | ((unsigned long long)(unsigned)src[e] << 21)
                       | ((unsigned long long)(unsigned)a << 38);
        }
    }
    int t = blockIdx.x * blockDim.x + threadIdx.x;
    if (t < (E & 3)) {
        int e = (E4 << 2) + t;
        int d = dst[e];
        if (getbit(f1bits, d)) {
            int a = slot_of[d];
            int pos = aoffs[a] + atomicAdd(&cursor[a], 1);
            apack[pos] = (unsigned long long)(unsigned)e
                       | ((unsigned long long)(unsigned)src[e] << 21)
                       | ((unsigned long long)(unsigned)a << 38);
        }
    }
}

// Layer-1 transforms, one launch: blocks [0,gb_dense) do dense xl1 = X@Wl1+bl1
// over all N rows; remaining blocks do gathered xr1c = X[f1node]@Wr1+br1.
__global__ __launch_bounds__(256)
void gemm1_fused_kernel(const float* __restrict__ X,
                        const float* __restrict__ Wl, const float* __restrict__ bl,
                        const float* __restrict__ Wr, const float* __restrict__ br,
                        const int* __restrict__ f1node,
                        const int* __restrict__ nf1_p,
                        int ndense, int gb_dense,
                        float* __restrict__ outl, float* __restrict__ outr)
{
    constexpr int K = 128, BM = 128, BK = 32, LDA = BM + 4;
    __shared__ float sW[K * 64];
    __shared__ float sA[BK * LDA];
    bool dense = (int)blockIdx.x < gb_dense;
    const float* W = dense ? Wl : Wr;
    const float* bias = dense ? bl : br;
    const int* rowlist = dense ? nullptr : f1node;
    float* out = dense ? outl : outr;
    int rows;
    if (dense) rows = ndense;
    else { rows = *nf1_p; if (rows > NF1CAP) rows = NF1CAP; }
    int bid = dense ? (int)blockIdx.x : (int)blockIdx.x - gb_dense;
    int base = bid * BM;
    if (base >= rows) return;
    int tid = threadIdx.x;
    for (int t = tid; t < K * 16; t += 256)
        ((float4*)sW)[t] = ((const float4*)W)[t];
    int tx = tid & 7, ty = tid >> 3;
    int c0 = tx * 8;
    float acc[4][8];
#pragma unroll
    for (int i = 0; i < 4; ++i)
#pragma unroll
        for (int j = 0; j < 8; ++j) acc[i][j] = 0.f;

    for (int kb = 0; kb < K; kb += BK) {
        __syncthreads();
#pragma unroll
        for (int q = 0; q < 4; ++q) {
            int lin = q * 256 + tid;
            int m = lin >> 3;
            int kk = (lin & 7) * 4;
            int rr = base + m;
            if (rr >= rows) rr = rows - 1;
            int grow = rowlist ? rowlist[rr] : rr;
            float4 v = *(const float4*)&X[(size_t)grow * K + kb + kk];
            sA[(kk + 0) * LDA + m] = v.x;
            sA[(kk + 1) * LDA + m] = v.y;
            sA[(kk + 2) * LDA + m] = v.z;
            sA[(kk + 3) * LDA + m] = v.w;
        }
        __syncthreads();
#pragma unroll
        for (int k = 0; k < BK; ++k) {
            float4 a4 = *(const float4*)&sA[k * LDA + ty * 4];
            float4 w0 = *(const float4*)&sW[(kb + k) * 64 + c0];
            float4 w1 = *(const float4*)&sW[(kb + k) * 64 + c0 + 4];
            float av[4] = {a4.x, a4.y, a4.z, a4.w};
            float wv[8] = {w0.x, w0.y, w0.z, w0.w, w1.x, w1.y, w1.z, w1.w};
#pragma unroll
            for (int i = 0; i < 4; ++i)
#pragma unroll
                for (int j = 0; j < 8; ++j)
                    acc[i][j] += av[i] * wv[j];
        }
    }
    float bv[8];
#pragma unroll
    for (int j = 0; j < 8; ++j) bv[j] = bias[c0 + j];
#pragma unroll
    for (int i = 0; i < 4; ++i) {
        int r = base + ty * 4 + i;
        if (r < rows) {
            float o[8];
#pragma unroll
            for (int j = 0; j < 8; ++j) o[j] = acc[i][j] + bv[j];
            *(float4*)&out[(size_t)r * 64 + c0] = *(float4*)&o[0];
            *(float4*)&out[(size_t)r * 64 + c0 + 4] = *(float4*)&o[4];
        }
    }
}

// Layer-2 transforms: both xl2c and xr2c in one pass over h1c (K=64).
__global__ __launch_bounds__(256)
void gemm2_both_kernel(const float* __restrict__ X,
                       const float* __restrict__ Wl, const float* __restrict__ bl,
                       const float* __restrict__ Wr, const float* __restrict__ br,
                       const int* __restrict__ nf1_p,
                       float* __restrict__ outl, float* __restrict__ outr)
{
    constexpr int K = 64, BM = 128, BK = 32, LDA = BM + 4;
    __shared__ float sW[2 * K * 64];
    __shared__ float sA[BK * LDA];
    int rows = *nf1_p; if (rows > NF1CAP) rows = NF1CAP;
    int base = (int)blockIdx.x * BM;
    if (base >= rows) return;
    int tid = threadIdx.x;
    for (int t = tid; t < K * 16; t += 256) {
        ((float4*)sW)[t] = ((const float4*)Wl)[t];
        ((float4*)sW)[K * 16 + t] = ((const float4*)Wr)[t];
    }
    int tx = tid & 7, ty = tid >> 3;
    int c0 = tx * 8;
    float accl[4][8], accr[4][8];
#pragma unroll
    for (int i = 0; i < 4; ++i)
#pragma unroll
        for (int j = 0; j < 8; ++j) { accl[i][j] = 0.f; accr[i][j] = 0.f; }

    for (int kb = 0; kb < K; kb += BK) {
        __syncthreads();
#pragma unroll
        for (int q = 0; q < 4; ++q) {
            int lin = q * 256 + tid;
            int m = lin >> 3;
            int kk = (lin & 7) * 4;
            int rr = base + m;
            if (rr >= rows) rr = rows - 1;
            float4 v = *(const float4*)&X[(size_t)rr * K + kb + kk];
            sA[(kk + 0) * LDA + m] = v.x;
            sA[(kk + 1) * LDA + m] = v.y;
            sA[(kk + 2) * LDA + m] = v.z;
            sA[(kk + 3) * LDA + m] = v.w;
        }
        __syncthreads();
#pragma unroll
        for (int k = 0; k < BK; ++k) {
            float4 a4 = *(const float4*)&sA[k * LDA + ty * 4];
            float4 l0 = *(const float4*)&sW[(kb + k) * 64 + c0];
            float4 l1 = *(const float4*)&sW[(kb + k) * 64 + c0 + 4];
            float4 r0 = *(const float4*)&sW[K * 64 + (kb + k) * 64 + c0];
            float4 r1 = *(const float4*)&sW[K * 64 + (kb + k) * 64 + c0 + 4];
            float av[4] = {a4.x, a4.y, a4.z, a4.w};
            float lv[8] = {l0.x, l0.y, l0.z, l0.w, l1.x, l1.y, l1.z, l1.w};
            float rv[8] = {r0.x, r0.y, r0.z, r0.w, r1.x, r1.y, r1.z, r1.w};
#pragma unroll
            for (int i = 0; i < 4; ++i)
#pragma unroll
                for (int j = 0; j < 8; ++j) {
                    accl[i][j] += av[i] * lv[j];
                    accr[i][j] += av[i] * rv[j];
                }
        }
    }
    float blv[8], brv[8];
#pragma unroll
    for (int j = 0; j < 8; ++j) { blv[j] = bl[c0 + j]; brv[j] = br[c0 + j]; }
#pragma unroll
    for (int i = 0; i < 4; ++i) {
        int r = base + ty * 4 + i;
        if (r < rows) {
            float ol[8], orr[8];
#pragma unroll
            for (int j = 0; j < 8; ++j) {
                ol[j] = accl[i][j] + blv[j];
                orr[j] = accr[i][j] + brv[j];
            }
            *(float4*)&outl[(size_t)r * 64 + c0] = *(float4*)&ol[0];
            *(float4*)&outl[(size_t)r * 64 + c0 + 4] = *(float4*)&ol[4];
            *(float4*)&outr[(size_t)r * 64 + c0] = *(float4*)&orr[0];
            *(float4*)&outr[(size_t)r * 64 + c0 + 4] = *(float4*)&orr[4];
        }
    }
}

// Fully fused layer-1 aggregation: one block per F1 node. Stages edge attrs
// in LDS once; computes edge logits (wave-strided), attr column sums (mean),
// chunked online softmax, self-loop, combine. -> h1c
__global__ __launch_bounds__(256)
void agg1_kernel(const int* __restrict__ nf1_p, const int* __restrict__ f1node,
                 const int* __restrict__ aoffs,
                 const unsigned long long* __restrict__ apack,
                 const float* __restrict__ eattr,
                 const float* __restrict__ xl, const float* __restrict__ xrc,
                 const float* __restrict__ We, const float* __restrict__ att,
                 const float* __restrict__ bias, float* __restrict__ h1c)
{
    constexpr int LDE = 36;
    __shared__ float sAttr[64 * LDE];
    __shared__ int   sSrc[64];
    __shared__ int   sEid[64];
    __shared__ float sLog[64];
    __shared__ float sRedM[4], sRedD[4];
    __shared__ float sCol[8][32];
    __shared__ float sMean[32];
    __shared__ float sAcc[4][64];

    int tid = threadIdx.x, lane = tid & 63, w = tid >> 6;
    float wec[32];
#pragma unroll
    for (int k = 0; k < 32; ++k) wec[k] = We[k * 64 + lane];
    float att_l = att[lane], bias_l = bias[lane];
    int n = *nf1_p; if (n > NF1CAP) n = NF1CAP;

    for (int a = blockIdx.x; a < n; a += gridDim.x) {
        int i = f1node[a];
        int beg = aoffs[a], deg = aoffs[a + 1] - beg;
        float xl_i = xl[(size_t)i * 64 + lane];
        float xr_i = xrc[(size_t)a * 64 + lane];
        float run_m = -3.0e38f, run_den = 0.f, accw = 0.f, colsum = 0.f;

        for (int t0 = 0; t0 < deg; t0 += 64) {
            int tn = deg - t0; if (tn > 64) tn = 64;
            __syncthreads();                       // shared-buffer reuse
            if (tid < tn) {
                unsigned long long rec = apack[beg + t0 + tid];
                sEid[tid] = (int)(rec & 0x1FFFFF);
                sSrc[tid] = (int)((rec >> 21) & 0x1FFFF);
            }
            __syncthreads();
#pragma unroll
            for (int q = 0; q < 2; ++q) {
                int lin = q * 256 + tid;
                int el = lin >> 3, quad = lin & 7;
                if (el < tn) {
                    float4 v = ((const float4*)(eattr
                                 + (size_t)sEid[el] * 32))[quad];
                    *(float4*)&sAttr[el * LDE + quad * 4] = v;
                }
            }
            __syncthreads();
            // attr column partial sums (for self-loop mean)
            for (int r = tid >> 5; r < tn; r += 8)
                colsum += sAttr[r * LDE + (tid & 31)];
            // edge logits, wave-strided for balance
            for (int j = w; j < tn; j += 4) {
                const float* ar = &sAttr[j * LDE];
                float emb = 0.f;
#pragma unroll
                for (int k = 0; k < 32; ++k) emb += ar[k] * wec[k];
                float m = xl[(size_t)sSrc[j] * 64 + lane] + xr_i + emb;
                m = (m >= 0.f) ? m : 0.2f * m;
                float pf = m * att_l;
#pragma unroll
                for (int d = 32; d; d >>= 1) pf += __shfl_xor(pf, d, 64);
                if (lane == 0) sLog[j] = pf;
            }
            __syncthreads();
            // block max
            float wm = (tid < tn) ? sLog[tid] : -3.0e38f;
#pragma unroll
            for (int d = 32; d; d >>= 1) wm = fmaxf(wm, __shfl_xor(wm, d, 64));
            if (lane == 0) sRedM[w] = wm;
            __syncthreads();
            float bm = fmaxf(fmaxf(sRedM[0], sRedM[1]),
                             fmaxf(sRedM[2], sRedM[3]));
            float newm = fmaxf(run_m, bm);
            // block denom for this tile
            float dp = (tid < tn) ? __expf(sLog[tid] - newm) : 0.f;
#pragma unroll
            for (int d = 32; d; d >>= 1) dp += __shfl_xor(dp, d, 64);
            if (lane == 0) sRedD[w] = dp;
            __syncthreads();
            float bden = sRedD[0] + sRedD[1] + sRedD[2] + sRedD[3];
            float sc = __expf(run_m - newm);
            accw *= sc;
            run_den = run_den * sc + bden;
            // weighted combine, 2 edges in flight per wave
            int j = w;
            for (; j + 8 <= tn + w; j += 8) {
                int j1 = j + 4;
                float w0 = __expf(sLog[j] - newm);
                float v0 = xl[(size_t)sSrc[j] * 64 + lane];
                float w1 = (j1 < tn) ? __expf(sLog[j1] - newm) : 0.f;
                float v1 = (j1 < tn) ? xl[(size_t)sSrc[j1] * 64 + lane] : 0.f;
                accw += w0 * v0;
                accw += w1 * v1;
            }
            for (; j < tn; j += 4) {
                float wgt = __expf(sLog[j] - newm);
                accw += wgt * xl[(size_t)sSrc[j] * 64 + lane];
            }
            run_m = newm;
        }
        // mean of incoming attrs
        sCol[tid >> 5][tid & 31] = colsum;
        __syncthreads();
        if (tid < 32) {
            float s = 0.f;
#pragma unroll
            for (int r = 0; r < 8; ++r) s += sCol[r][tid];
            sMean[tid] = s / (float)(deg > 0 ? deg : 1);
        }
        __syncthreads();
        // self-loop logit (uniform across waves)
        float embs = 0.f;
#pragma unroll
        for (int k = 0; k < 32; ++k) embs += sMean[k] * wec[k];
        float ms = xl_i + xr_i + embs;
        ms = (ms >= 0.f) ? ms : 0.2f * ms;
        float pf = ms * att_l;
#pragma unroll
        for (int d = 32; d; d >>= 1) pf += __shfl_xor(pf, d, 64);
        float slog = pf;
        float newm = fmaxf(run_m, slog);
        float sc = __expf(run_m - newm);
        float wself = __expf(slog - newm);
        float den = run_den * sc + wself;
        sAcc[w][lane] = accw * sc;
        __syncthreads();
        float tot = sAcc[0][lane] + sAcc[1][lane] + sAcc[2][lane]
                  + sAcc[3][lane] + wself * xl_i;
        h1c[(size_t)a * 64 + lane] = fmaxf(tot / den + bias_l, 0.f);
        __syncthreads();
    }
}

// Fully fused layer-2 tail: one block per selected node. Edge logits + mean +
// online softmax + combine + MLP head -> out.
__global__ __launch_bounds__(256)
void tail2_kernel(const int* __restrict__ nidx, const int* __restrict__ slot_of,
                  const int* __restrict__ aoffs,
                  const unsigned long long* __restrict__ apack,
                  const float* __restrict__ eattr,
                  const float* __restrict__ xl2c, const float* __restrict__ xr2c,
                  const float* __restrict__ We, const float* __restrict__ att,
                  const float* __restrict__ bias, const float* __restrict__ y,
                  const float* __restrict__ W0, const float* __restrict__ b0,
                  const float* __restrict__ W1, const float* __restrict__ b1,
                  const float* __restrict__ W2, const float* __restrict__ b2,
                  float* __restrict__ out, int nsel, int rf)
{
    constexpr int LDE = 36;
    __shared__ float sAttr[64 * LDE];
    __shared__ int   sSrc[64];       // src SLOT (layer-2 rows are compact)
    __shared__ int   sEid[64];
    __shared__ float sLog[64];
    __shared__ float sRedM[4], sRedD[4];
    __shared__ float sCol[8][32];
    __shared__ float sMean[32];
    __shared__ float sAcc[4][64];

    int tid = threadIdx.x, lane = tid & 63, w = tid >> 6;
    float wec[32];
#pragma unroll
    for (int k = 0; k < 32; ++k) wec[k] = We[k * 64 + lane];
    float att_l = att[lane], bias_l = bias[lane];

    for (int r = blockIdx.x; r < nsel; r += gridDim.x) {
        int i = nidx[r];
        int a = slot_of[i];
        int beg = aoffs[a], deg = aoffs[a + 1] - beg;
        float xl_i = xl2c[(size_t)a * 64 + lane];
        float xr_i = xr2c[(size_t)a * 64 + lane];
        float run_m = -3.0e38f, run_den = 0.f, accw = 0.f, colsum = 0.f;

        for (int t0 = 0; t0 < deg; t0 += 64) {
            int tn = deg - t0; if (tn > 64) tn = 64;
            __syncthreads();
            if (tid < tn) {
                unsigned long long rec = apack[beg + t0 + tid];
                sEid[tid] = (int)(rec & 0x1FFFFF);
                sSrc[tid] = slot_of[(int)((rec >> 21) & 0x1FFFF)];
            }
            __syncthreads();
#pragma unroll
            for (int q = 0; q < 2; ++q) {
                int lin = q * 256 + tid;
                int el = lin >> 3, quad = lin & 7;
                if (el < tn) {
                    float4 v = ((const float4*)(eattr
                                 + (size_t)sEid[el] * 32))[quad];
                    *(float4*)&sAttr[el * LDE + quad * 4] = v;
                }
            }
            __syncthreads();
            for (int rr = tid >> 5; rr < tn; rr += 8)
                colsum += sAttr[rr * LDE + (tid & 31)];
            for (int j = w; j < tn; j += 4) {
                const float* ar = &sAttr[j * LDE];
                float emb = 0.f;
#pragma unroll
                for (int k = 0; k < 32; ++k) emb += ar[k] * wec[k];
                float m = xl2c[(size_t)sSrc[j] * 64 + lane] + xr_i + emb;
                m = (m >= 0.f) ? m : 0.2f * m;
                float pf = m * att_l;
#pragma unroll
                for (int d = 32; d; d >>= 1) pf += __shfl_xor(pf, d, 64);
                if (lane == 0) sLog[j] = pf;
            }
            __syncthreads();
            float wm = (tid < tn) ? sLog[tid] : -3.0e38f;
#pragma unroll
            for (int d = 32; d; d >>= 1) wm = fmaxf(wm, __shfl_xor(wm, d, 64));
            if (lane == 0) sRedM[w] = wm;
            __syncthreads();
            float bm = fmaxf(fmaxf(sRedM[0], sRedM[1]),
                             fmaxf(sRedM[2], sRedM[3]));
            float newm = fmaxf(run_m, bm);
            float dp = (tid < tn) ? __expf(sLog[tid] - newm) : 0.f;
#pragma unroll
            for (int d = 32; d; d >>= 1) dp += __shfl_xor(dp, d, 64);
            if (lane == 0) sRedD[w] = dp;
            __syncthreads();
            float bden = sRedD[0] + sRedD[1] + sRedD[2] + sRedD[3];
            float sc = __expf(run_m - newm);
            accw *= sc;
            run_den = run_den * sc + bden;
            for (int j = w; j < tn; j += 4) {
                float wgt = __expf(sLog[j] - newm);
                accw += wgt * xl2c[(size_t)sSrc[j] * 64 + lane];
            }
            run_m = newm;
        }
        sCol[tid >> 5][tid & 31] = colsum;
        __syncthreads();
        if (tid < 32) {
            float s = 0.f;
#pragma unroll
            for (int rr = 0; rr < 8; ++rr) s += sCol[rr][tid];
            sMean[tid] = s / (float)(deg > 0 ? deg : 1);
        }
        __syncthreads();
        float embs = 0.f;
#pragma unroll
        for (int k = 0; k < 32; ++k) embs += sMean[k] * wec[k];
        float ms = xl_i + xr_i + embs;
        ms = (ms >= 0.f) ? ms : 0.2f * ms;
        float pf = ms * att_l;
#pragma unroll
        for (int d = 32; d; d >>= 1) pf += __shfl_xor(pf, d, 64);
        float slog = pf;
        float newm = fmaxf(run_m, slog);
        float sc = __expf(run_m - newm);
        float wself = __expf(slog - newm);
        float den = run_den * sc + wself;
        sAcc[w][lane] = accw * sc;
        __syncthreads();
        float tot = sAcc[0][lane] + sAcc[1][lane] + sAcc[2][lane]
                  + sAcc[3][lane] + wself * xl_i;
        float h = fmaxf(tot / den + bias_l, 0.f);   // per lane, all waves
        // MLP head (all waves compute redundantly; wave 0 writes)
        int yi = i / rf;
        float y0 = y[2 * yi], y1 = y[2 * yi + 1];
        float t0v = fmaxf(y0 * W0[0] + y1 * W0[2] + b0[0], 0.f);
        float t1v = fmaxf(y0 * W0[1] + y1 * W0[3] + b0[1], 0.f);
        int j = lane & 31;
        float acc = b1[j];
#pragma unroll
        for (int k = 0; k < 64; ++k) acc += __shfl(h, k, 64) * W1[k * 32 + j];
        acc += t0v * W1[64 * 32 + j] + t1v * W1[65 * 32 + j];
        acc = fmaxf(acc, 0.f);
        float res = b2[j];
#pragma unroll
        for (int k = 0; k < 32; ++k) res += __shfl(acc, k, 64) * W2[k * 32 + j];
        if (w == 0 && lane < 32) out[(size_t)r * 32 + j] = res;
        __syncthreads();
    }
}

extern "C" void kernel_launch(void* const* d_in, const int* in_sizes, int n_in,
                              void* d_out, int out_size, void* d_ws,
                              size_t ws_size, hipStream_t stream)
{
    const float* x     = (const float*)d_in[0];
    const float* eattr = (const float*)d_in[1];
    const float* y     = (const float*)d_in[2];
    const float* Wl1 = (const float*)d_in[3],  *bl1 = (const float*)d_in[4];
    const float* Wr1 = (const float*)d_in[5],  *br1 = (const float*)d_in[6];
    const float* We1 = (const float*)d_in[7],  *att1 = (const float*)d_in[8];
    const float* bias1 = (const float*)d_in[9];
    const float* Wl2 = (const float*)d_in[10], *bl2 = (const float*)d_in[11];
    const float* Wr2 = (const float*)d_in[12], *br2 = (const float*)d_in[13];
    const float* We2 = (const float*)d_in[14], *att2 = (const float*)d_in[15];
    const float* bias2 = (const float*)d_in[16];
    const float* W0 = (const float*)d_in[17], *b0 = (const float*)d_in[18];
    const float* W1 = (const float*)d_in[19], *b1 = (const float*)d_in[20];
    const float* W2 = (const float*)d_in[21], *b2 = (const float*)d_in[22];
    const int* eidx = (const int*)d_in[23];
    const int* nidx = (const int*)d_in[24];

    const int N = in_sizes[0] / 128;
    const int E = in_sizes[1] / 32;
    const int NSEL = in_sizes[24];
    const int NGr = in_sizes[2] / 2;
    const int rf = N / NGr;

    const int* src = eidx;
    const int* dst = eidx + E;

    size_t off = 0;
    auto alloc = [&](size_t nb) {
        size_t r = off;
        off += (nb + 255) & ~(size_t)255;
        return r;
    };
    char* ws = (char*)d_ws;
    const int NBW = (N + 31) / 32;

    // ---- zero-init region (one memset) ----
    unsigned* selbits = (unsigned*)(ws + alloc((size_t)NBW * 4));
    unsigned* f1bits  = (unsigned*)(ws + alloc((size_t)NBW * 4));
    int* indeg  = (int*)(ws + alloc((size_t)N * 4));
    int* cursor = (int*)(ws + alloc((size_t)NF1CAP * 4));
    int* ctrs   = (int*)(ws + alloc(256));  // [0]=nf1 [1]=ne1
    size_t zero_bytes = off;
    // ---- rest ----
    int* slot_of = (int*)(ws + alloc((size_t)N * 4));
    int* f1node  = (int*)(ws + alloc((size_t)NF1CAP * 4));
    int* aoffs   = (int*)(ws + alloc((size_t)(NF1CAP + 1) * 4));
    unsigned long long* apack =
        (unsigned long long*)(ws + alloc((size_t)E * 8));
    float* xl1  = (float*)(ws + alloc((size_t)N * 64 * 4));
    float* xr1c = (float*)(ws + alloc((size_t)NF1CAP * 64 * 4));
    float* h1c  = (float*)(ws + alloc((size_t)NF1CAP * 64 * 4));
    float* xl2c = (float*)(ws + alloc((size_t)NF1CAP * 64 * 4));
    float* xr2c = (float*)(ws + alloc((size_t)NF1CAP * 64 * 4));
    (void)ws_size;

    int* nf1_p = ctrs + 0;
    int* ne1_p = ctrs + 1;

    hipMemsetAsync(ws, 0, zero_bytes, stream);

    // frontier + compact CSR (packed records)
    mark_sel_kernel<<<(NSEL + 255) / 256, 256, 0, stream>>>(nidx, selbits,
                                                            f1bits, NSEL);
    pass_a_kernel<<<2048, 256, 0, stream>>>(src, dst, selbits, f1bits, indeg, E);
    compact_f1_kernel<<<(N + 255) / 256, 256, 0, stream>>>(f1bits, nf1_p,
                                                           f1node, slot_of, N);
    scan_kernel<<<1, 1024, 0, stream>>>(indeg, f1node, nf1_p, NF1CAP, aoffs,
                                        ne1_p);
    scatter_kernel<<<2048, 256, 0, stream>>>(src, dst, f1bits, slot_of, aoffs,
                                             cursor, apack, E);
    // layer-1 transforms (one launch: dense xl1 + gathered xr1c)
    {
        int gb_dense = (N + 127) / 128;
        int gb_total = gb_dense + NF1CAP / 128;
        gemm1_fused_kernel<<<gb_total, 256, 0, stream>>>(
            x, Wl1, bl1, Wr1, br1, f1node, nf1_p, N, gb_dense, xl1, xr1c);
    }
    // layer-1 fused aggregation
    agg1_kernel<<<4096, 256, 0, stream>>>(nf1_p, f1node, aoffs, apack, eattr,
                                          xl1, xr1c, We1, att1, bias1, h1c);
    // layer-2 transforms (both in one pass over h1c)
    gemm2_both_kernel<<<NF1CAP / 128, 256, 0, stream>>>(h1c, Wl2, bl2, Wr2,
                                                        br2, nf1_p, xl2c, xr2c);
    // layer-2 fused aggregation + MLP head
    tail2_kernel<<<NSEL, 256, 0, stream>>>(nidx, slot_of, aoffs, apack, eattr,
                                           xl2c, xr2c, We2, att2, bias2, y,
                                           W0, b0, W1, b1, W2, b2,
                                           (float*)d_out, NSEL, rf);
}

// Round 10
// 569.555 us; speedup vs baseline: 2.2653x; 1.1772x over previous
//
#include <hip/hip_runtime.h>

// ---------------------------------------------------------------------------
// GATv2 x2 + MLP head, output at node_idx (1000 rows).
// Frontier-compact pipeline, packed-record CSR, tiled f32 GEMMs, and
// WAVE-PER-NODE barrier-free aggregation (wave-private LDS attr staging,
// online softmax, self-loop emb via linearity: mean(attr)@We = mean(attr@We)).
// ---------------------------------------------------------------------------

#define NF1CAP 24576   // cap on |F1| (expected ~15.6k)

__device__ __forceinline__ int getbit(const unsigned* b, int i) {
    return (b[i >> 5] >> (i & 31)) & 1;
}

__global__ __launch_bounds__(256)
void mark_sel_kernel(const int* __restrict__ nidx, unsigned* __restrict__ selbits,
                     unsigned* __restrict__ f1bits, int n)
{
    int t = blockIdx.x * blockDim.x + threadIdx.x;
    if (t < n) {
        int i = nidx[t];
        atomicOr(&selbits[i >> 5], 1u << (i & 31));
        atomicOr(&f1bits[i >> 5], 1u << (i & 31));
    }
}

// E-scan 1: mark srcs of edges whose dst is selected (completes f1bits)
__global__ __launch_bounds__(256)
void pass_mark_kernel(const int* __restrict__ src, const int* __restrict__ dst,
                      const unsigned* __restrict__ selbits,
                      unsigned* __restrict__ f1bits, int E)
{
    int E4 = E >> 2;
    for (int i = blockIdx.x * blockDim.x + threadIdx.x; i < E4;
         i += gridDim.x * blockDim.x) {
        int4 d4 = ((const int4*)dst)[i];
        int dd[4] = {d4.x, d4.y, d4.z, d4.w};
#pragma unroll
        for (int j = 0; j < 4; ++j) {
            if (getbit(selbits, dd[j])) {
                int s = src[i * 4 + j];
                atomicOr(&f1bits[s >> 5], 1u << (s & 31));
            }
        }
    }
    int t = blockIdx.x * blockDim.x + threadIdx.x;
    if (t < (E & 3)) {
        int e = (E4 << 2) + t;
        if (getbit(selbits, dst[e])) {
            int s = src[e];
            atomicOr(&f1bits[s >> 5], 1u << (s & 31));
        }
    }
}

// E-scan 2: in-degree histogram, F1 dsts only (~264k atomics, not 1.6M)
__global__ __launch_bounds__(256)
void pass_hist_kernel(const int* __restrict__ dst,
                      const unsigned* __restrict__ f1bits,
                      int* __restrict__ indeg, int E)
{
    int E4 = E >> 2;
    for (int i = blockIdx.x * blockDim.x + threadIdx.x; i < E4;
         i += gridDim.x * blockDim.x) {
        int4 d4 = ((const int4*)dst)[i];
        int dd[4] = {d4.x, d4.y, d4.z, d4.w};
#pragma unroll
        for (int j = 0; j < 4; ++j)
            if (getbit(f1bits, dd[j])) atomicAdd(&indeg[dd[j]], 1);
    }
    int t = blockIdx.x * blockDim.x + threadIdx.x;
    if (t < (E & 3)) {
        int e = (E4 << 2) + t;
        int d = dst[e];
        if (getbit(f1bits, d)) atomicAdd(&indeg[d], 1);
    }
}

__global__ __launch_bounds__(256)
void compact_f1_kernel(const unsigned* __restrict__ f1bits, int* __restrict__ nf1,
                       int* __restrict__ f1node, int* __restrict__ slot_of, int n)
{
    int i = blockIdx.x * blockDim.x + threadIdx.x;
    if (i >= n) return;
    if (getbit(f1bits, i)) {
        int s = atomicAdd(nf1, 1);
        if (s < NF1CAP) { f1node[s] = i; slot_of[i] = s; }
        else slot_of[i] = 0;
    }
}

__global__ __launch_bounds__(1024)
void scan_kernel(const int* __restrict__ indeg, const int* __restrict__ f1node,
                 const int* __restrict__ n_ptr, int cap,
                 int* __restrict__ offs, int* __restrict__ ne_out)
{
    __shared__ int buf[1024];
    int n = *n_ptr; if (n > cap) n = cap;
    int tid = threadIdx.x;
    int chunk = (n + 1023) / 1024;
    int base = tid * chunk;
    int s = 0;
    for (int j = 0; j < chunk; ++j) {
        int idx = base + j;
        if (idx < n) s += indeg[f1node[idx]];
    }
    buf[tid] = s;
    __syncthreads();
    for (int off = 1; off < 1024; off <<= 1) {
        int v = (tid >= off) ? buf[tid - off] : 0;
        __syncthreads();
        buf[tid] += v;
        __syncthreads();
    }
    int run = (tid > 0) ? buf[tid - 1] : 0;
    for (int j = 0; j < chunk; ++j) {
        int idx = base + j;
        if (idx < n) { offs[idx] = run; run += indeg[f1node[idx]]; }
    }
    if (tid == 1023) { offs[n] = buf[1023]; *ne_out = buf[1023]; }
}

// packed record: eid[0:21) | src[21:38) | slot[38:53)
__global__ __launch_bounds__(256)
void scatter_kernel(const int* __restrict__ src, const int* __restrict__ dst,
                    const unsigned* __restrict__ f1bits,
                    const int* __restrict__ slot_of, const int* __restrict__ aoffs,
                    int* __restrict__ cursor,
                    unsigned long long* __restrict__ apack, int E)
{
    int E4 = E >> 2;
    for (int i = blockIdx.x * blockDim.x + threadIdx.x; i < E4;
         i += gridDim.x * blockDim.x) {
        int4 d4 = ((const int4*)dst)[i];
        int dd[4] = {d4.x, d4.y, d4.z, d4.w};
#pragma unroll
        for (int j = 0; j < 4; ++j) {
            int d = dd[j];
            if (!getbit(f1bits, d)) continue;
            int a = slot_of[d];
            int pos = aoffs[a] + atomicAdd(&cursor[a], 1);
            int e = i * 4 + j;
            apack[pos] = (unsigned long long)(unsigned)e
                       | ((unsigned long long)(unsigned)src[e] << 21)
                       | ((unsigned long long)(unsigned)a << 38);
        }
    }
    int t = blockIdx.x * blockDim.x + threadIdx.x;
    if (t < (E & 3)) {
        int e = (E4 << 2) + t;
        int d = dst[e];
        if (getbit(f1bits, d)) {
            int a = slot_of[d];
            int pos = aoffs[a] + atomicAdd(&cursor[a], 1);
            apack[pos] = (unsigned long long)(unsigned)e
                       | ((unsigned long long)(unsigned)src[e] << 21)
                       | ((unsigned long long)(unsigned)a << 38);
        }
    }
}

// Layer-1 transforms, one launch: blocks [0,gb_dense) do dense xl1 = X@Wl1+bl1
// over all N rows; remaining blocks do gathered xr1c = X[f1node]@Wr1+br1.
__global__ __launch_bounds__(256)
void gemm1_fused_kernel(const float* __restrict__ X,
                        const float* __restrict__ Wl, const float* __restrict__ bl,
                        const float* __restrict__ Wr, const float* __restrict__ br,
                        const int* __restrict__ f1node,
                        const int* __restrict__ nf1_p,
                        int ndense, int gb_dense,
                        float* __restrict__ outl, float* __restrict__ outr)
{
    constexpr int K = 128, BM = 128, BK = 32, LDA = BM + 4;
    __shared__ float sW[K * 64];
    __shared__ float sA[BK * LDA];
    bool dense = (int)blockIdx.x < gb_dense;
    const float* W = dense ? Wl : Wr;
    const float* bias = dense ? bl : br;
    const int* rowlist = dense ? nullptr : f1node;
    float* out = dense ? outl : outr;
    int rows;
    if (dense) rows = ndense;
    else { rows = *nf1_p; if (rows > NF1CAP) rows = NF1CAP; }
    int bid = dense ? (int)blockIdx.x : (int)blockIdx.x - gb_dense;
    int base = bid * BM;
    if (base >= rows) return;
    int tid = threadIdx.x;
    for (int t = tid; t < K * 16; t += 256)
        ((float4*)sW)[t] = ((const float4*)W)[t];
    int tx = tid & 7, ty = tid >> 3;
    int c0 = tx * 8;
    float acc[4][8];
#pragma unroll
    for (int i = 0; i < 4; ++i)
#pragma unroll
        for (int j = 0; j < 8; ++j) acc[i][j] = 0.f;

    for (int kb = 0; kb < K; kb += BK) {
        __syncthreads();
#pragma unroll
        for (int q = 0; q < 4; ++q) {
            int lin = q * 256 + tid;
            int m = lin >> 3;
            int kk = (lin & 7) * 4;
            int rr = base + m;
            if (rr >= rows) rr = rows - 1;
            int grow = rowlist ? rowlist[rr] : rr;
            float4 v = *(const float4*)&X[(size_t)grow * K + kb + kk];
            sA[(kk + 0) * LDA + m] = v.x;
            sA[(kk + 1) * LDA + m] = v.y;
            sA[(kk + 2) * LDA + m] = v.z;
            sA[(kk + 3) * LDA + m] = v.w;
        }
        __syncthreads();
#pragma unroll
        for (int k = 0; k < BK; ++k) {
            float4 a4 = *(const float4*)&sA[k * LDA + ty * 4];
            float4 w0 = *(const float4*)&sW[(kb + k) * 64 + c0];
            float4 w1 = *(const float4*)&sW[(kb + k) * 64 + c0 + 4];
            float av[4] = {a4.x, a4.y, a4.z, a4.w};
            float wv[8] = {w0.x, w0.y, w0.z, w0.w, w1.x, w1.y, w1.z, w1.w};
#pragma unroll
            for (int i = 0; i < 4; ++i)
#pragma unroll
                for (int j = 0; j < 8; ++j)
                    acc[i][j] += av[i] * wv[j];
        }
    }
    float bv[8];
#pragma unroll
    for (int j = 0; j < 8; ++j) bv[j] = bias[c0 + j];
#pragma unroll
    for (int i = 0; i < 4; ++i) {
        int r = base + ty * 4 + i;
        if (r < rows) {
            float o[8];
#pragma unroll
            for (int j = 0; j < 8; ++j) o[j] = acc[i][j] + bv[j];
            *(float4*)&out[(size_t)r * 64 + c0] = *(float4*)&o[0];
            *(float4*)&out[(size_t)r * 64 + c0 + 4] = *(float4*)&o[4];
        }
    }
}

// Layer-2 transforms: both xl2c and xr2c in one pass over h1c (K=64).
__global__ __launch_bounds__(256)
void gemm2_both_kernel(const float* __restrict__ X,
                       const float* __restrict__ Wl, const float* __restrict__ bl,
                       const float* __restrict__ Wr, const float* __restrict__ br,
                       const int* __restrict__ nf1_p,
                       float* __restrict__ outl, float* __restrict__ outr)
{
    constexpr int K = 64, BM = 128, BK = 32, LDA = BM + 4;
    __shared__ float sW[2 * K * 64];
    __shared__ float sA[BK * LDA];
    int rows = *nf1_p; if (rows > NF1CAP) rows = NF1CAP;
    int base = (int)blockIdx.x * BM;
    if (base >= rows) return;
    int tid = threadIdx.x;
    for (int t = tid; t < K * 16; t += 256) {
        ((float4*)sW)[t] = ((const float4*)Wl)[t];
        ((float4*)sW)[K * 16 + t] = ((const float4*)Wr)[t];
    }
    int tx = tid & 7, ty = tid >> 3;
    int c0 = tx * 8;
    float accl[4][8], accr[4][8];
#pragma unroll
    for (int i = 0; i < 4; ++i)
#pragma unroll
        for (int j = 0; j < 8; ++j) { accl[i][j] = 0.f; accr[i][j] = 0.f; }

    for (int kb = 0; kb < K; kb += BK) {
        __syncthreads();
#pragma unroll
        for (int q = 0; q < 4; ++q) {
            int lin = q * 256 + tid;
            int m = lin >> 3;
            int kk = (lin & 7) * 4;
            int rr = base + m;
            if (rr >= rows) rr = rows - 1;
            float4 v = *(const float4*)&X[(size_t)rr * K + kb + kk];
            sA[(kk + 0) * LDA + m] = v.x;
            sA[(kk + 1) * LDA + m] = v.y;
            sA[(kk + 2) * LDA + m] = v.z;
            sA[(kk + 3) * LDA + m] = v.w;
        }
        __syncthreads();
#pragma unroll
        for (int k = 0; k < BK; ++k) {
            float4 a4 = *(const float4*)&sA[k * LDA + ty * 4];
            float4 l0 = *(const float4*)&sW[(kb + k) * 64 + c0];
            float4 l1 = *(const float4*)&sW[(kb + k) * 64 + c0 + 4];
            float4 r0 = *(const float4*)&sW[K * 64 + (kb + k) * 64 + c0];
            float4 r1 = *(const float4*)&sW[K * 64 + (kb + k) * 64 + c0 + 4];
            float av[4] = {a4.x, a4.y, a4.z, a4.w};
            float lv[8] = {l0.x, l0.y, l0.z, l0.w, l1.x, l1.y, l1.z, l1.w};
            float rv[8] = {r0.x, r0.y, r0.z, r0.w, r1.x, r1.y, r1.z, r1.w};
#pragma unroll
            for (int i = 0; i < 4; ++i)
#pragma unroll
                for (int j = 0; j < 8; ++j) {
                    accl[i][j] += av[i] * lv[j];
                    accr[i][j] += av[i] * rv[j];
                }
        }
    }
    float blv[8], brv[8];
#pragma unroll
    for (int j = 0; j < 8; ++j) { blv[j] = bl[c0 + j]; brv[j] = br[c0 + j]; }
#pragma unroll
    for (int i = 0; i < 4; ++i) {
        int r = base + ty * 4 + i;
        if (r < rows) {
            float ol[8], orr[8];
#pragma unroll
            for (int j = 0; j < 8; ++j) {
                ol[j] = accl[i][j] + blv[j];
                orr[j] = accr[i][j] + brv[j];
            }
            *(float4*)&outl[(size_t)r * 64 + c0] = *(float4*)&ol[0];
            *(float4*)&outl[(size_t)r * 64 + c0 + 4] = *(float4*)&ol[4];
            *(float4*)&outr[(size_t)r * 64 + c0] = *(float4*)&orr[0];
            *(float4*)&outr[(size_t)r * 64 + c0 + 4] = *(float4*)&orr[4];
        }
    }
}

// Wave-per-node layer-1 aggregation, barrier-free. Self-loop emb via
// linearity: emb_self = (sum_e emb_e)/deg.
__global__ __launch_bounds__(256)
void agg1_kernel(const int* __restrict__ nf1_p, const int* __restrict__ f1node,
                 const int* __restrict__ aoffs,
                 const unsigned long long* __restrict__ apack,
                 const float* __restrict__ eattr,
                 const float* __restrict__ xl, const float* __restrict__ xrc,
                 const float* __restrict__ We, const float* __restrict__ att,
                 const float* __restrict__ bias, float* __restrict__ h1c)
{
    __shared__ float sAttr[4 * 16 * 36];    // per-wave private slice
    int tid = threadIdx.x, lane = tid & 63, w = tid >> 6;
    float* myAttr = &sAttr[w * 16 * 36];
    float wec[32];
#pragma unroll
    for (int k = 0; k < 32; ++k) wec[k] = We[k * 64 + lane];
    float att_l = att[lane], bias_l = bias[lane];
    int n = *nf1_p; if (n > NF1CAP) n = NF1CAP;
    int gwid = (blockIdx.x * 256 + tid) >> 6;
    int nwaves = (gridDim.x * 256) >> 6;

    for (int a = gwid; a < n; a += nwaves) {
        int i = f1node[a];
        int beg = aoffs[a], deg = aoffs[a + 1] - beg;
        float xl_i = xl[(size_t)i * 64 + lane];
        float xr_i = xrc[(size_t)a * 64 + lane];
        float run_m = -3.0e38f, run_den = 0.f, accw = 0.f, embsum = 0.f;

        for (int t0 = 0; t0 < deg; t0 += 16) {
            int rem = deg - t0; if (rem > 16) rem = 16;
            unsigned long long rec = 0;
            if (lane < rem) rec = apack[beg + t0 + lane];
            int eidv = (int)(rec & 0x1FFFFF);
            int srcv = (int)((rec >> 21) & 0x1FFFF);
            asm volatile("" ::: "memory");   // order vs prev-iter LDS reads
            // stage rem attr rows into wave slice (2 coalesced float4 rounds)
#pragma unroll
            for (int q = 0; q < 2; ++q) {
                int row = (lane >> 3) + q * 8;
                int quad = lane & 7;
                int rowc = (row < rem) ? row : rem - 1;
                int e = __shfl(eidv, rowc, 64);
                float4 v = ((const float4*)(eattr + (size_t)e * 32))[quad];
                *(float4*)&myAttr[row * 36 + quad * 4] = v;
            }
            asm volatile("" ::: "memory");   // order writes before reads
            for (int j = 0; j < rem; ++j) {
                const float* ar = &myAttr[j * 36];
                float emb = 0.f;
#pragma unroll
                for (int k = 0; k < 32; ++k) emb += ar[k] * wec[k];
                embsum += emb;
                int s = __shfl(srcv, j, 64);
                float xls = xl[(size_t)s * 64 + lane];
                float m = xls + xr_i + emb;
                m = (m >= 0.f) ? m : 0.2f * m;
                float pf = m * att_l;
#pragma unroll
                for (int d = 32; d; d >>= 1) pf += __shfl_xor(pf, d, 64);
                float newm = fmaxf(run_m, pf);
                float sc = __expf(run_m - newm);
                float wgt = __expf(pf - newm);
                accw = accw * sc + wgt * xls;
                run_den = run_den * sc + wgt;
                run_m = newm;
            }
        }
        // self-loop
        float inv = 1.0f / (float)(deg > 0 ? deg : 1);
        float ms = xl_i + xr_i + embsum * inv;
        ms = (ms >= 0.f) ? ms : 0.2f * ms;
        float pf = ms * att_l;
#pragma unroll
        for (int d = 32; d; d >>= 1) pf += __shfl_xor(pf, d, 64);
        float newm = fmaxf(run_m, pf);
        float sc = __expf(run_m - newm);
        float wself = __expf(pf - newm);
        accw = accw * sc + wself * xl_i;
        float den = run_den * sc + wself;
        h1c[(size_t)a * 64 + lane] = fmaxf(accw / den + bias_l, 0.f);
    }
}

// Wave-per-selected-node layer-2 aggregation + MLP head, barrier-free.
__global__ __launch_bounds__(256)
void tail2_kernel(const int* __restrict__ nidx, const int* __restrict__ slot_of,
                  const int* __restrict__ aoffs,
                  const unsigned long long* __restrict__ apack,
                  const float* __restrict__ eattr,
                  const float* __restrict__ xl2c, const float* __restrict__ xr2c,
                  const float* __restrict__ We, const float* __restrict__ att,
                  const float* __restrict__ bias, const float* __restrict__ y,
                  const float* __restrict__ W0, const float* __restrict__ b0,
                  const float* __restrict__ W1, const float* __restrict__ b1,
                  const float* __restrict__ W2, const float* __restrict__ b2,
                  float* __restrict__ out, int nsel, int rf)
{
    __shared__ float sAttr[4 * 16 * 36];
    int tid = threadIdx.x, lane = tid & 63, w = tid >> 6;
    float* myAttr = &sAttr[w * 16 * 36];
    float wec[32];
#pragma unroll
    for (int k = 0; k < 32; ++k) wec[k] = We[k * 64 + lane];
    float att_l = att[lane], bias_l = bias[lane];
    int gwid = (blockIdx.x * 256 + tid) >> 6;
    int nwaves = (gridDim.x * 256) >> 6;

    for (int r = gwid; r < nsel; r += nwaves) {
        int i = nidx[r];
        int a = slot_of[i];
        int beg = aoffs[a], deg = aoffs[a + 1] - beg;
        float xl_i = xl2c[(size_t)a * 64 + lane];
        float xr_i = xr2c[(size_t)a * 64 + lane];
        float run_m = -3.0e38f, run_den = 0.f, accw = 0.f, embsum = 0.f;

        for (int t0 = 0; t0 < deg; t0 += 16) {
            int rem = deg - t0; if (rem > 16) rem = 16;
            unsigned long long rec = 0;
            if (lane < rem) rec = apack[beg + t0 + lane];
            int eidv = (int)(rec & 0x1FFFFF);
            int srcv = (int)((rec >> 21) & 0x1FFFF);
            asm volatile("" ::: "memory");
#pragma unroll
            for (int q = 0; q < 2; ++q) {
                int row = (lane >> 3) + q * 8;
                int quad = lane & 7;
                int rowc = (row < rem) ? row : rem - 1;
                int e = __shfl(eidv, rowc, 64);
                float4 v = ((const float4*)(eattr + (size_t)e * 32))[quad];
                *(float4*)&myAttr[row * 36 + quad * 4] = v;
            }
            asm volatile("" ::: "memory");
            for (int j = 0; j < rem; ++j) {
                const float* ar = &myAttr[j * 36];
                float emb = 0.f;
#pragma unroll
                for (int k = 0; k < 32; ++k) emb += ar[k] * wec[k];
                embsum += emb;
                int s = __shfl(srcv, j, 64);
                int sslot = slot_of[s];
                float xls = xl2c[(size_t)sslot * 64 + lane];
                float m = xls + xr_i + emb;
                m = (m >= 0.f) ? m : 0.2f * m;
                float pf = m * att_l;
#pragma unroll
                for (int d = 32; d; d >>= 1) pf += __shfl_xor(pf, d, 64);
                float newm = fmaxf(run_m, pf);
                float sc = __expf(run_m - newm);
                float wgt = __expf(pf - newm);
                accw = accw * sc + wgt * xls;
                run_den = run_den * sc + wgt;
                run_m = newm;
            }
        }
        float inv = 1.0f / (float)(deg > 0 ? deg : 1);
        float ms = xl_i + xr_i + embsum * inv;
        ms = (ms >= 0.f) ? ms : 0.2f * ms;
        float pf = ms * att_l;
#pragma unroll
        for (int d = 32; d; d >>= 1) pf += __shfl_xor(pf, d, 64);
        float newm = fmaxf(run_m, pf);
        float sc = __expf(run_m - newm);
        float wself = __expf(pf - newm);
        accw = accw * sc + wself * xl_i;
        float den = run_den * sc + wself;
        float h = fmaxf(accw / den + bias_l, 0.f);
        // MLP head (per wave)
        int yi = i / rf;
        float y0 = y[2 * yi], y1 = y[2 * yi + 1];
        float t0v = fmaxf(y0 * W0[0] + y1 * W0[2] + b0[0], 0.f);
        float t1v = fmaxf(y0 * W0[1] + y1 * W0[3] + b0[1], 0.f);
        int j = lane & 31;
        float acc = b1[j];
#pragma unroll
        for (int k = 0; k < 64; ++k) acc += __shfl(h, k, 64) * W1[k * 32 + j];
        acc += t0v * W1[64 * 32 + j] + t1v * W1[65 * 32 + j];
        acc = fmaxf(acc, 0.f);
        float res = b2[j];
#pragma unroll
        for (int k = 0; k < 32; ++k) res += __shfl(acc, k, 64) * W2[k * 32 + j];
        if (lane < 32) out[(size_t)r * 32 + j] = res;
    }
}

extern "C" void kernel_launch(void* const* d_in, const int* in_sizes, int n_in,
                              void* d_out, int out_size, void* d_ws,
                              size_t ws_size, hipStream_t stream)
{
    const float* x     = (const float*)d_in[0];
    const float* eattr = (const float*)d_in[1];
    const float* y     = (const float*)d_in[2];
    const float* Wl1 = (const float*)d_in[3],  *bl1 = (const float*)d_in[4];
    const float* Wr1 = (const float*)d_in[5],  *br1 = (const float*)d_in[6];
    const float* We1 = (const float*)d_in[7],  *att1 = (const float*)d_in[8];
    const float* bias1 = (const float*)d_in[9];
    const float* Wl2 = (const float*)d_in[10], *bl2 = (const float*)d_in[11];
    const float* Wr2 = (const float*)d_in[12], *br2 = (const float*)d_in[13];
    const float* We2 = (const float*)d_in[14], *att2 = (const float*)d_in[15];
    const float* bias2 = (const float*)d_in[16];
    const float* W0 = (const float*)d_in[17], *b0 = (const float*)d_in[18];
    const float* W1 = (const float*)d_in[19], *b1 = (const float*)d_in[20];
    const float* W2 = (const float*)d_in[21], *b2 = (const float*)d_in[22];
    const int* eidx = (const int*)d_in[23];
    const int* nidx = (const int*)d_in[24];

    const int N = in_sizes[0] / 128;
    const int E = in_sizes[1] / 32;
    const int NSEL = in_sizes[24];
    const int NGr = in_sizes[2] / 2;
    const int rf = N / NGr;

    const int* src = eidx;
    const int* dst = eidx + E;

    size_t off = 0;
    auto alloc = [&](size_t nb) {
        size_t r = off;
        off += (nb + 255) & ~(size_t)255;
        return r;
    };
    char* ws = (char*)d_ws;
    const int NBW = (N + 31) / 32;

    // ---- zero-init region (one memset) ----
    unsigned* selbits = (unsigned*)(ws + alloc((size_t)NBW * 4));
    unsigned* f1bits  = (unsigned*)(ws + alloc((size_t)NBW * 4));
    int* indeg  = (int*)(ws + alloc((size_t)N * 4));
    int* cursor = (int*)(ws + alloc((size_t)NF1CAP * 4));
    int* ctrs   = (int*)(ws + alloc(256));  // [0]=nf1 [1]=ne1
    size_t zero_bytes = off;
    // ---- rest ----
    int* slot_of = (int*)(ws + alloc((size_t)N * 4));
    int* f1node  = (int*)(ws + alloc((size_t)NF1CAP * 4));
    int* aoffs   = (int*)(ws + alloc((size_t)(NF1CAP + 1) * 4));
    unsigned long long* apack =
        (unsigned long long*)(ws + alloc((size_t)E * 8));
    float* xl1  = (float*)(ws + alloc((size_t)N * 64 * 4));
    float* xr1c = (float*)(ws + alloc((size_t)NF1CAP * 64 * 4));
    float* h1c  = (float*)(ws + alloc((size_t)NF1CAP * 64 * 4));
    float* xl2c = (float*)(ws + alloc((size_t)NF1CAP * 64 * 4));
    float* xr2c = (float*)(ws + alloc((size_t)NF1CAP * 64 * 4));
    (void)ws_size;

    int* nf1_p = ctrs + 0;
    int* ne1_p = ctrs + 1;

    hipMemsetAsync(ws, 0, zero_bytes, stream);

    // frontier + compact CSR (packed records)
    mark_sel_kernel<<<(NSEL + 255) / 256, 256, 0, stream>>>(nidx, selbits,
                                                            f1bits, NSEL);
    pass_mark_kernel<<<2048, 256, 0, stream>>>(src, dst, selbits, f1bits, E);
    pass_hist_kernel<<<2048, 256, 0, stream>>>(dst, f1bits, indeg, E);
    compact_f1_kernel<<<(N + 255) / 256, 256, 0, stream>>>(f1bits, nf1_p,
                                                           f1node, slot_of, N);
    scan_kernel<<<1, 1024, 0, stream>>>(indeg, f1node, nf1_p, NF1CAP, aoffs,
                                        ne1_p);
    scatter_kernel<<<2048, 256, 0, stream>>>(src, dst, f1bits, slot_of, aoffs,
                                             cursor, apack, E);
    // layer-1 transforms (one launch: dense xl1 + gathered xr1c)
    {
        int gb_dense = (N + 127) / 128;
        int gb_total = gb_dense + NF1CAP / 128;
        gemm1_fused_kernel<<<gb_total, 256, 0, stream>>>(
            x, Wl1, bl1, Wr1, br1, f1node, nf1_p, N, gb_dense, xl1, xr1c);
    }
    // layer-1 wave-per-node aggregation
    agg1_kernel<<<1024, 256, 0, stream>>>(nf1_p, f1node, aoffs, apack, eattr,
                                          xl1, xr1c, We1, att1, bias1, h1c);
    // layer-2 transforms (both in one pass over h1c)
    gemm2_both_kernel<<<NF1CAP / 128, 256, 0, stream>>>(h1c, Wl2, bl2, Wr2,
                                                        br2, nf1_p, xl2c, xr2c);
    // layer-2 wave-per-node aggregation + MLP head
    tail2_kernel<<<(NSEL + 3) / 4, 256, 0, stream>>>(
        nidx, slot_of, aoffs, apack, eattr, xl2c, xr2c, We2, att2, bias2, y,
        W0, b0, W1, b1, W2, b2, (float*)d_out, NSEL, rf);
}